// Round 1
// baseline (814.158 us; speedup 1.0000x reference)
//
#include <hip/hip_runtime.h>

// Problem constants (from reference)
#define NN 50000
#define EE 800000
#define KIN 512
#define HF 256      // H*OUT
#define NH 8
#define FOUT 32
#define NC 16
#define NEG 0.2f

__device__ __forceinline__ float lrelu(float x) { return x > 0.f ? x : NEG * x; }

// ---------------- CSR build ----------------
__global__ void count_deg(const int* __restrict__ dst, int* __restrict__ deg) {
    int e = blockIdx.x * 256 + threadIdx.x;
    if (e < EE) atomicAdd(&deg[dst[e]], 1);
}

__global__ __launch_bounds__(1024) void scan_offsets(const int* __restrict__ deg, int* __restrict__ off) {
    __shared__ int sums[1024];
    int t = threadIdx.x;
    const int chunk = (NN + 1023) / 1024;  // 49
    int start = t * chunk;
    int end = start + chunk; if (end > NN) end = NN;
    int s = 0;
    for (int i = start; i < end; i++) s += deg[i];
    sums[t] = s;
    __syncthreads();
    for (int d = 1; d < 1024; d <<= 1) {
        int v = 0;
        if (t >= d) v = sums[t - d];
        __syncthreads();
        sums[t] += v;
        __syncthreads();
    }
    int run = (t == 0) ? 0 : sums[t - 1];
    for (int i = start; i < end; i++) { off[i] = run; run += deg[i]; }
    if (t == 1023) off[NN] = sums[1023];
}

__global__ void fill_csr(const int* __restrict__ src, const int* __restrict__ dst,
                         const int* __restrict__ off, int* __restrict__ cursor,
                         int* __restrict__ csr_src) {
    int e = blockIdx.x * 256 + threadIdx.x;
    if (e < EE) {
        int d = dst[e];
        int pos = atomicAdd(&cursor[d], 1);
        csr_src[off[d] + pos] = src[e];
    }
}

// ---------------- GEMM1: h1[N,256] = x[N,512] @ W1[512,256], fp32 ----------------
__global__ __launch_bounds__(256) void gemm1(const float* __restrict__ A, const float* __restrict__ B,
                                             float* __restrict__ Cm) {
    const int M = NN, K = KIN, Nc = HF;
    __shared__ float As[16][128];  // k-major
    __shared__ float Bs[16][128];
    int t = threadIdx.x;
    int bm = blockIdx.x * 128;
    int bn = blockIdx.y * 128;
    int tm = t >> 4, tn = t & 15;
    int ar = t >> 1, ac = (t & 1) * 8;
    int br = t >> 4, bc = (t & 15) * 8;
    float acc[8][8];
#pragma unroll
    for (int i = 0; i < 8; i++)
#pragma unroll
        for (int j = 0; j < 8; j++) acc[i][j] = 0.f;

    for (int kk = 0; kk < K; kk += 16) {
        float4 a0 = make_float4(0, 0, 0, 0), a1 = make_float4(0, 0, 0, 0);
        int grow = bm + ar;
        if (grow < M) {
            const float* ap = A + (size_t)grow * K + kk + ac;
            a0 = *(const float4*)ap;
            a1 = *(const float4*)(ap + 4);
        }
        const float* bp = B + (size_t)(kk + br) * Nc + bn + bc;
        float4 b0 = *(const float4*)bp;
        float4 b1 = *(const float4*)(bp + 4);
        __syncthreads();
        As[ac + 0][ar] = a0.x; As[ac + 1][ar] = a0.y; As[ac + 2][ar] = a0.z; As[ac + 3][ar] = a0.w;
        As[ac + 4][ar] = a1.x; As[ac + 5][ar] = a1.y; As[ac + 6][ar] = a1.z; As[ac + 7][ar] = a1.w;
        *(float4*)&Bs[br][bc] = b0;
        *(float4*)&Bs[br][bc + 4] = b1;
        __syncthreads();
#pragma unroll
        for (int k = 0; k < 16; k++) {
            float av[8], bv[8];
            *(float4*)&av[0] = *(const float4*)&As[k][tm * 8];
            *(float4*)&av[4] = *(const float4*)&As[k][tm * 8 + 4];
            *(float4*)&bv[0] = *(const float4*)&Bs[k][tn * 8];
            *(float4*)&bv[4] = *(const float4*)&Bs[k][tn * 8 + 4];
#pragma unroll
            for (int i = 0; i < 8; i++)
#pragma unroll
                for (int j = 0; j < 8; j++) acc[i][j] += av[i] * bv[j];
        }
    }
#pragma unroll
    for (int i = 0; i < 8; i++) {
        int gr = bm + tm * 8 + i;
        if (gr < M) {
            float* cp = Cm + (size_t)gr * Nc + bn + tn * 8;
            *(float4*)cp = make_float4(acc[i][0], acc[i][1], acc[i][2], acc[i][3]);
            *(float4*)(cp + 4) = make_float4(acc[i][4], acc[i][5], acc[i][6], acc[i][7]);
        }
    }
}

// ---------------- per-node attention scores layer 1 ----------------
__global__ __launch_bounds__(256) void scores1(const float* __restrict__ h1, const float* __restrict__ a_src,
                                               const float* __restrict__ a_dst,
                                               float* __restrict__ es, float* __restrict__ ed) {
    int n = blockIdx.x, t = threadIdx.x;
    float v = h1[(size_t)n * HF + t];
    float ps = v * a_src[t];
    float pd = v * a_dst[t];
#pragma unroll
    for (int o = 16; o; o >>= 1) {
        ps += __shfl_down(ps, o, 32);
        pd += __shfl_down(pd, o, 32);
    }
    if ((t & 31) == 0) {
        es[n * NH + (t >> 5)] = ps;
        ed[n * NH + (t >> 5)] = pd;
    }
}

// ---------------- layer-1 softmax + aggregate (+ ELU), block = 1 dst node ----------------
__global__ __launch_bounds__(256) void agg1(const float* __restrict__ h1, const float* __restrict__ es,
                                            const float* __restrict__ ed, const int* __restrict__ off,
                                            const int* __restrict__ csr_src, float* __restrict__ out1) {
    int n = blockIdx.x, t = threadIdx.x;
    __shared__ float edl[NH], m_h[NH], s_h[NH];
    __shared__ float p_chunk[32][NH];
    __shared__ int src_chunk[32];
    int beg = off[n];
    int deg = off[n + 1] - beg;
    if (t < NH) edl[t] = ed[n * NH + t];
    __syncthreads();
    int h = t >> 5;    // 0..7
    int le = t & 31;   // edge lane
    float mx = -3.0e38f;
    for (int e = le; e < deg; e += 32) {
        int s = csr_src[beg + e];
        mx = fmaxf(mx, lrelu(es[s * NH + h] + edl[h]));
    }
#pragma unroll
    for (int o = 16; o; o >>= 1) mx = fmaxf(mx, __shfl_down(mx, o, 32));
    if (le == 0) m_h[h] = mx;
    __syncthreads();
    float mh = m_h[h];
    float sm = 0.f;
    for (int e = le; e < deg; e += 32) {
        int s = csr_src[beg + e];
        sm += __expf(lrelu(es[s * NH + h] + edl[h]) - mh);
    }
#pragma unroll
    for (int o = 16; o; o >>= 1) sm += __shfl_down(sm, o, 32);
    if (le == 0) s_h[h] = sm;
    __syncthreads();
    int hh = t >> 5;
    float inv_s = s_h[hh] > 0.f ? 1.0f / s_h[hh] : 0.f;
    float acc = 0.f;
    for (int base = 0; base < deg; base += 32) {
        int nch = deg - base; if (nch > 32) nch = 32;
        __syncthreads();
        if (t < nch * 8) {
            int el = t >> 3, h2 = t & 7;
            int s = csr_src[beg + base + el];
            p_chunk[el][h2] = __expf(lrelu(es[s * NH + h2] + edl[h2]) - m_h[h2]);
            if (h2 == 0) src_chunk[el] = s;
        }
        __syncthreads();
        for (int el = 0; el < nch; el++) {
            acc += p_chunk[el][hh] * h1[(size_t)src_chunk[el] * HF + t];
        }
    }
    float v = acc * inv_s;
    out1[(size_t)n * HF + t] = v > 0.f ? v : (__expf(v) - 1.0f);  // fused ELU
}

// ---------------- GEMM2 + layer-2 scores: h2[N,16] = elu_out1[N,256] @ W2[256,16] ----------------
__global__ __launch_bounds__(256) void gemm2(const float* __restrict__ out1, const float* __restrict__ W2,
                                             const float* __restrict__ a2s, const float* __restrict__ a2d,
                                             float* __restrict__ h2, float* __restrict__ es2,
                                             float* __restrict__ ed2) {
    __shared__ float rows[16][257];   // +1 pad: avoids 16-way bank conflict on rows[nl][k]
    __shared__ float w[256][16];
    int t = threadIdx.x;
    int nb = blockIdx.x * 16;
    for (int i = t; i < 256 * 16; i += 256) ((float*)w)[i] = W2[i];
    for (int r = 0; r < 16; r++) rows[r][t] = out1[(size_t)(nb + r) * HF + t];
    __syncthreads();
    int nl = t >> 4, c = t & 15;
    float acc = 0.f;
#pragma unroll 8
    for (int k = 0; k < 256; k++) acc += rows[nl][k] * w[k][c];
    int n = nb + nl;
    h2[n * NC + c] = acc;
    float ps = acc * a2s[c];
    float pd = acc * a2d[c];
#pragma unroll
    for (int o = 8; o; o >>= 1) {
        ps += __shfl_down(ps, o, 16);
        pd += __shfl_down(pd, o, 16);
    }
    if (c == 0) { es2[n] = ps; ed2[n] = pd; }
}

// ---------------- layer-2 softmax + aggregate + log_softmax, block(64) = 1 dst node ----------------
__global__ __launch_bounds__(64) void agg2(const float* __restrict__ h2, const float* __restrict__ es2,
                                           const float* __restrict__ ed2, const int* __restrict__ off,
                                           const int* __restrict__ csr_src, float* __restrict__ out) {
    int n = blockIdx.x, t = threadIdx.x;
    int beg = off[n];
    int deg = off[n + 1] - beg;
    float edn = ed2[n];
    float mx = -3.0e38f;
    for (int e = t; e < deg; e += 64) {
        mx = fmaxf(mx, lrelu(es2[csr_src[beg + e]] + edn));
    }
#pragma unroll
    for (int o = 32; o; o >>= 1) mx = fmaxf(mx, __shfl_down(mx, o, 64));
    mx = __shfl(mx, 0, 64);
    float sm = 0.f;
    for (int e = t; e < deg; e += 64) {
        sm += __expf(lrelu(es2[csr_src[beg + e]] + edn) - mx);
    }
#pragma unroll
    for (int o = 32; o; o >>= 1) sm += __shfl_down(sm, o, 64);
    sm = __shfl(sm, 0, 64);
    float inv_s = sm > 0.f ? 1.0f / sm : 0.f;
    int slot = t >> 4, c = t & 15;
    float acc = 0.f;
    for (int e = slot; e < deg; e += 4) {
        int s = csr_src[beg + e];
        float p = __expf(lrelu(es2[s] + edn) - mx);
        acc += p * h2[s * NC + c];
    }
    acc += __shfl_down(acc, 32, 64);
    acc += __shfl_down(acc, 16, 64);
    __shared__ float vals[16];
    if (t < 16) vals[c] = acc * inv_s;
    __syncthreads();
    if (t < 16) {
        float v = vals[t];
        float m2 = v;
#pragma unroll
        for (int o = 8; o; o >>= 1) m2 = fmaxf(m2, __shfl_down(m2, o, 16));
        m2 = __shfl(m2, 0, 16);
        float se = __expf(v - m2);
#pragma unroll
        for (int o = 8; o; o >>= 1) se += __shfl_down(se, o, 16);
        se = __shfl(se, 0, 16);
        out[n * NC + t] = v - m2 - __logf(se);
    }
}

extern "C" void kernel_launch(void* const* d_in, const int* in_sizes, int n_in,
                              void* d_out, int out_size, void* d_ws, size_t ws_size,
                              hipStream_t stream) {
    const float* x   = (const float*)d_in[0];
    const float* W1  = (const float*)d_in[1];
    const float* a1s = (const float*)d_in[2];
    const float* a1d = (const float*)d_in[3];
    const float* W2  = (const float*)d_in[4];
    const float* a2s = (const float*)d_in[5];
    const float* a2d = (const float*)d_in[6];
    const int*   ei  = (const int*)d_in[7];
    const int* srcv = ei;
    const int* dstv = ei + EE;
    float* out = (float*)d_out;

    // workspace layout (~110 MB)
    float* h1   = (float*)d_ws;                       // N*256
    float* out1 = h1 + (size_t)NN * HF;               // N*256
    float* es1  = out1 + (size_t)NN * HF;             // N*8
    float* ed1  = es1 + (size_t)NN * NH;              // N*8
    float* h2   = ed1 + (size_t)NN * NH;              // N*16
    float* es2v = h2 + (size_t)NN * NC;               // N
    float* ed2v = es2v + NN;                          // N
    int* deg    = (int*)(ed2v + NN);                  // N
    int* cursor = deg + NN;                           // N
    int* offs   = cursor + NN;                        // N+1
    int* csr    = offs + NN + 1;                      // E

    hipMemsetAsync(deg, 0, NN * sizeof(int), stream);
    hipMemsetAsync(cursor, 0, NN * sizeof(int), stream);
    count_deg<<<(EE + 255) / 256, 256, 0, stream>>>(dstv, deg);
    scan_offsets<<<1, 1024, 0, stream>>>(deg, offs);
    fill_csr<<<(EE + 255) / 256, 256, 0, stream>>>(srcv, dstv, offs, cursor, csr);
    gemm1<<<dim3((NN + 127) / 128, HF / 128), 256, 0, stream>>>(x, W1, h1);
    scores1<<<NN, 256, 0, stream>>>(h1, a1s, a1d, es1, ed1);
    agg1<<<NN, 256, 0, stream>>>(h1, es1, ed1, offs, csr, out1);
    gemm2<<<NN / 16, 256, 0, stream>>>(out1, W2, a2s, a2d, h2, es2v, ed2v);
    agg2<<<NN, 64, 0, stream>>>(h2, es2v, ed2v, offs, csr, out);
}

// Round 2
// 603.760 us; speedup vs baseline: 1.3485x; 1.3485x over previous
//
#include <hip/hip_runtime.h>

// Problem constants (from reference)
#define NN 50000
#define EE 800000
#define KIN 512
#define HF 256      // H*OUT
#define NH 8
#define FOUT 32
#define NC 16
#define NEG 0.2f

typedef unsigned short u16;
typedef __attribute__((ext_vector_type(8))) short shortx8;   // 8 bf16 (4 VGPRs) MFMA A/B frag
typedef __attribute__((ext_vector_type(4))) float floatx4;   // MFMA C/D frag
typedef __attribute__((ext_vector_type(8))) unsigned short ushortx8;

__device__ __forceinline__ float lrelu(float x) { return x > 0.f ? x : NEG * x; }

__device__ __forceinline__ u16 f2bf(float f) {
    unsigned u = __float_as_uint(f);
    return (u16)((u + 0x7FFFu + ((u >> 16) & 1u)) >> 16);   // RNE
}

__device__ __forceinline__ void gll16(const void* g, void* l) {
    // async global->LDS, 16B/lane; LDS dest = wave-uniform base + lane*16
    __builtin_amdgcn_global_load_lds((const __attribute__((address_space(1))) void*)g,
                                     (__attribute__((address_space(3))) void*)l, 16, 0, 0);
}

// ---------------- CSR build ----------------
__global__ void count_deg(const int* __restrict__ dst, int* __restrict__ deg) {
    int e = blockIdx.x * 256 + threadIdx.x;
    if (e < EE) atomicAdd(&deg[dst[e]], 1);
}

__global__ __launch_bounds__(1024) void scan_offsets(const int* __restrict__ deg, int* __restrict__ off) {
    __shared__ int sums[1024];
    int t = threadIdx.x;
    const int chunk = (NN + 1023) / 1024;  // 49
    int start = t * chunk;
    int end = start + chunk; if (end > NN) end = NN;
    int s = 0;
    for (int i = start; i < end; i++) s += deg[i];
    sums[t] = s;
    __syncthreads();
    for (int d = 1; d < 1024; d <<= 1) {
        int v = 0;
        if (t >= d) v = sums[t - d];
        __syncthreads();
        sums[t] += v;
        __syncthreads();
    }
    int run = (t == 0) ? 0 : sums[t - 1];
    for (int i = start; i < end; i++) { off[i] = run; run += deg[i]; }
    if (t == 1023) off[NN] = sums[1023];
}

__global__ void fill_csr(const int* __restrict__ src, const int* __restrict__ dst,
                         const int* __restrict__ off, int* __restrict__ cursor,
                         int* __restrict__ csr_src) {
    int e = blockIdx.x * 256 + threadIdx.x;
    if (e < EE) {
        int d = dst[e];
        int pos = atomicAdd(&cursor[d], 1);
        csr_src[off[d] + pos] = src[e];
    }
}

// ---------------- converts for bf16 GEMM1 ----------------
// x [N,512] fp32 -> xb [N,512] bf16 (8 elems/thread)
__global__ __launch_bounds__(256) void convert_x(const float* __restrict__ x, u16* __restrict__ xb) {
    size_t i = ((size_t)blockIdx.x * 256 + threadIdx.x) * 8;
    if (i >= (size_t)NN * KIN) return;
    float4 f0 = *(const float4*)(x + i);
    float4 f1 = *(const float4*)(x + i + 4);
    ushortx8 o;
    o[0] = f2bf(f0.x); o[1] = f2bf(f0.y); o[2] = f2bf(f0.z); o[3] = f2bf(f0.w);
    o[4] = f2bf(f1.x); o[5] = f2bf(f1.y); o[6] = f2bf(f1.z); o[7] = f2bf(f1.w);
    *(ushortx8*)(xb + i) = o;
}

// W1 [512,256] fp32 -> W1T [256,512] bf16
__global__ __launch_bounds__(256) void convert_w1t(const float* __restrict__ W1, u16* __restrict__ w1t) {
    int e = blockIdx.x * 256 + threadIdx.x;   // 512*256 = 131072
    int k = e >> 8, n = e & 255;
    w1t[n * KIN + k] = f2bf(W1[e]);
}

// ---------------- GEMM1 (bf16 MFMA): h1[N,256] = xb[N,512] @ W1T^T ----------------
// 128x128 tile, BK=32, 4 waves each 4x4 of 16x16x32 MFMA tiles (m97 structure)
__global__ __launch_bounds__(256) void gemm1_mfma(const u16* __restrict__ xb,
                                                  const u16* __restrict__ w1t,
                                                  float* __restrict__ h1) {
    __shared__ __align__(16) u16 As[128 * 32];   // [row][k] 8 KB
    __shared__ __align__(16) u16 Bs[128 * 32];   // [col][k] 8 KB
    int t = threadIdx.x;
    int lane = t & 63, wave = t >> 6;
    int wm = wave >> 1, wn = wave & 1;
    int lm = lane & 15, quad = lane >> 4;
    int bm = blockIdx.x * 128;
    int bn = blockIdx.y * 128;

    floatx4 acc[4][4];
#pragma unroll
    for (int i = 0; i < 4; i++)
#pragma unroll
        for (int j = 0; j < 4; j++) acc[i][j] = (floatx4){0.f, 0.f, 0.f, 0.f};

    // staging: wave w covers rows [w*32, w*32+32) of the tile, 2 insts of 64 lanes x 16B
    int sr = wave * 32 + (lane >> 2);         // local row for q=0 (q=1: +16)
    int sk = (lane & 3) * 8;                  // k offset (elements)
    int ar0 = bm + sr, ar1 = ar0 + 16;
    if (ar0 > NN - 1) ar0 = NN - 1;           // clamp tail rows (dup reads, outputs unguarded only in LDS)
    if (ar1 > NN - 1) ar1 = NN - 1;
    const u16* agp0 = xb + (size_t)ar0 * KIN + sk;
    const u16* agp1 = xb + (size_t)ar1 * KIN + sk;
    const u16* bgp0 = w1t + (size_t)(bn + sr) * KIN + sk;
    const u16* bgp1 = w1t + (size_t)(bn + sr + 16) * KIN + sk;
    u16* asl0 = As + wave * 1024;             // wave-uniform LDS bases (elements)
    u16* asl1 = As + wave * 1024 + 512;
    u16* bsl0 = Bs + wave * 1024;
    u16* bsl1 = Bs + wave * 1024 + 512;

    // fragment read offsets (elements)
    int offA[4], offB[4];
#pragma unroll
    for (int i = 0; i < 4; i++) offA[i] = (wm * 64 + i * 16 + lm) * 32 + quad * 8;
#pragma unroll
    for (int j = 0; j < 4; j++) offB[j] = (wn * 64 + j * 16 + lm) * 32 + quad * 8;

    for (int kk = 0; kk < KIN; kk += 32) {
        gll16(agp0 + kk, asl0);
        gll16(agp1 + kk, asl1);
        gll16(bgp0 + kk, bsl0);
        gll16(bgp1 + kk, bsl1);
        __syncthreads();   // drains vmcnt(0): staged data visible
        shortx8 af[4], bf[4];
#pragma unroll
        for (int i = 0; i < 4; i++) af[i] = *(const shortx8*)&As[offA[i]];
#pragma unroll
        for (int j = 0; j < 4; j++) bf[j] = *(const shortx8*)&Bs[offB[j]];
#pragma unroll
        for (int i = 0; i < 4; i++)
#pragma unroll
            for (int j = 0; j < 4; j++)
                acc[i][j] = __builtin_amdgcn_mfma_f32_16x16x32_bf16(af[i], bf[j], acc[i][j], 0, 0, 0);
        __syncthreads();   // all reads done before next stage overwrites
    }

    // epilogue: C/D map col=lane&15, row=quad*4+reg
#pragma unroll
    for (int i = 0; i < 4; i++) {
        int row = bm + wm * 64 + i * 16 + quad * 4;
#pragma unroll
        for (int j = 0; j < 4; j++) {
            int col = bn + wn * 64 + j * 16 + lm;
#pragma unroll
            for (int r = 0; r < 4; r++) {
                if (row + r < NN) h1[(size_t)(row + r) * HF + col] = acc[i][j][r];
            }
        }
    }
}

// ---------------- per-node attention scores layer 1 ----------------
__global__ __launch_bounds__(256) void scores1(const float* __restrict__ h1, const float* __restrict__ a_src,
                                               const float* __restrict__ a_dst,
                                               float* __restrict__ es, float* __restrict__ ed) {
    int n = blockIdx.x, t = threadIdx.x;
    float v = h1[(size_t)n * HF + t];
    float ps = v * a_src[t];
    float pd = v * a_dst[t];
#pragma unroll
    for (int o = 16; o; o >>= 1) {
        ps += __shfl_down(ps, o, 32);
        pd += __shfl_down(pd, o, 32);
    }
    if ((t & 31) == 0) {
        es[n * NH + (t >> 5)] = ps;
        ed[n * NH + (t >> 5)] = pd;
    }
}

// ---------------- layer-1 softmax + aggregate (+ ELU), block = 1 dst node ----------------
__global__ __launch_bounds__(256) void agg1(const float* __restrict__ h1, const float* __restrict__ es,
                                            const float* __restrict__ ed, const int* __restrict__ off,
                                            const int* __restrict__ csr_src, float* __restrict__ out1) {
    int n = blockIdx.x, t = threadIdx.x;
    __shared__ float edl[NH], m_h[NH], s_h[NH];
    __shared__ float p_chunk[32][NH];
    __shared__ int src_chunk[32];
    int beg = off[n];
    int deg = off[n + 1] - beg;
    if (t < NH) edl[t] = ed[n * NH + t];
    __syncthreads();
    int h = t >> 5;    // 0..7
    int le = t & 31;   // edge lane
    float mx = -3.0e38f;
    for (int e = le; e < deg; e += 32) {
        int s = csr_src[beg + e];
        mx = fmaxf(mx, lrelu(es[s * NH + h] + edl[h]));
    }
#pragma unroll
    for (int o = 16; o; o >>= 1) mx = fmaxf(mx, __shfl_down(mx, o, 32));
    if (le == 0) m_h[h] = mx;
    __syncthreads();
    float mh = m_h[h];
    float sm = 0.f;
    for (int e = le; e < deg; e += 32) {
        int s = csr_src[beg + e];
        sm += __expf(lrelu(es[s * NH + h] + edl[h]) - mh);
    }
#pragma unroll
    for (int o = 16; o; o >>= 1) sm += __shfl_down(sm, o, 32);
    if (le == 0) s_h[h] = sm;
    __syncthreads();
    int hh = t >> 5;
    float inv_s = s_h[hh] > 0.f ? 1.0f / s_h[hh] : 0.f;
    float acc = 0.f;
    for (int base = 0; base < deg; base += 32) {
        int nch = deg - base; if (nch > 32) nch = 32;
        __syncthreads();
        if (t < nch * 8) {
            int el = t >> 3, h2 = t & 7;
            int s = csr_src[beg + base + el];
            p_chunk[el][h2] = __expf(lrelu(es[s * NH + h2] + edl[h2]) - m_h[h2]);
            if (h2 == 0) src_chunk[el] = s;
        }
        __syncthreads();
        for (int el = 0; el < nch; el++) {
            acc += p_chunk[el][hh] * h1[(size_t)src_chunk[el] * HF + t];
        }
    }
    float v = acc * inv_s;
    out1[(size_t)n * HF + t] = v > 0.f ? v : (__expf(v) - 1.0f);  // fused ELU
}

// ---------------- GEMM2 + layer-2 scores ----------------
__global__ __launch_bounds__(256) void gemm2(const float* __restrict__ out1, const float* __restrict__ W2,
                                             const float* __restrict__ a2s, const float* __restrict__ a2d,
                                             float* __restrict__ h2, float* __restrict__ es2,
                                             float* __restrict__ ed2) {
    __shared__ float rows[16][257];   // +1 pad: avoids 16-way bank conflict on rows[nl][k]
    __shared__ float w[256][16];
    int t = threadIdx.x;
    int nb = blockIdx.x * 16;
    for (int i = t; i < 256 * 16; i += 256) ((float*)w)[i] = W2[i];
    for (int r = 0; r < 16; r++) rows[r][t] = out1[(size_t)(nb + r) * HF + t];
    __syncthreads();
    int nl = t >> 4, c = t & 15;
    float acc = 0.f;
#pragma unroll 8
    for (int k = 0; k < 256; k++) acc += rows[nl][k] * w[k][c];
    int n = nb + nl;
    h2[n * NC + c] = acc;
    float ps = acc * a2s[c];
    float pd = acc * a2d[c];
#pragma unroll
    for (int o = 8; o; o >>= 1) {
        ps += __shfl_down(ps, o, 16);
        pd += __shfl_down(pd, o, 16);
    }
    if (c == 0) { es2[n] = ps; ed2[n] = pd; }
}

// ---------------- layer-2 softmax + aggregate + log_softmax ----------------
__global__ __launch_bounds__(64) void agg2(const float* __restrict__ h2, const float* __restrict__ es2,
                                           const float* __restrict__ ed2, const int* __restrict__ off,
                                           const int* __restrict__ csr_src, float* __restrict__ out) {
    int n = blockIdx.x, t = threadIdx.x;
    int beg = off[n];
    int deg = off[n + 1] - beg;
    float edn = ed2[n];
    float mx = -3.0e38f;
    for (int e = t; e < deg; e += 64) {
        mx = fmaxf(mx, lrelu(es2[csr_src[beg + e]] + edn));
    }
#pragma unroll
    for (int o = 32; o; o >>= 1) mx = fmaxf(mx, __shfl_down(mx, o, 64));
    mx = __shfl(mx, 0, 64);
    float sm = 0.f;
    for (int e = t; e < deg; e += 64) {
        sm += __expf(lrelu(es2[csr_src[beg + e]] + edn) - mx);
    }
#pragma unroll
    for (int o = 32; o; o >>= 1) sm += __shfl_down(sm, o, 64);
    sm = __shfl(sm, 0, 64);
    float inv_s = sm > 0.f ? 1.0f / sm : 0.f;
    int slot = t >> 4, c = t & 15;
    float acc = 0.f;
    for (int e = slot; e < deg; e += 4) {
        int s = csr_src[beg + e];
        float p = __expf(lrelu(es2[s] + edn) - mx);
        acc += p * h2[s * NC + c];
    }
    acc += __shfl_down(acc, 32, 64);
    acc += __shfl_down(acc, 16, 64);
    __shared__ float vals[16];
    if (t < 16) vals[c] = acc * inv_s;
    __syncthreads();
    if (t < 16) {
        float v = vals[t];
        float m2 = v;
#pragma unroll
        for (int o = 8; o; o >>= 1) m2 = fmaxf(m2, __shfl_down(m2, o, 16));
        m2 = __shfl(m2, 0, 16);
        float se = __expf(v - m2);
#pragma unroll
        for (int o = 8; o; o >>= 1) se += __shfl_down(se, o, 16);
        se = __shfl(se, 0, 16);
        out[n * NC + t] = v - m2 - __logf(se);
    }
}

extern "C" void kernel_launch(void* const* d_in, const int* in_sizes, int n_in,
                              void* d_out, int out_size, void* d_ws, size_t ws_size,
                              hipStream_t stream) {
    const float* x   = (const float*)d_in[0];
    const float* W1  = (const float*)d_in[1];
    const float* a1s = (const float*)d_in[2];
    const float* a1d = (const float*)d_in[3];
    const float* W2  = (const float*)d_in[4];
    const float* a2s = (const float*)d_in[5];
    const float* a2d = (const float*)d_in[6];
    const int*   ei  = (const int*)d_in[7];
    const int* srcv = ei;
    const int* dstv = ei + EE;
    float* out = (float*)d_out;

    // workspace layout (~107 MB); xb aliases out1 (disjoint lifetimes, both 51.2 MB);
    // w1t aliases h2 (w1t dead before gemm2 writes h2)
    float* h1   = (float*)d_ws;                       // N*256 fp32
    float* out1 = h1 + (size_t)NN * HF;               // N*256 fp32
    u16*   xb   = (u16*)out1;                         // N*512 bf16 == out1 bytes exactly
    float* es1  = out1 + (size_t)NN * HF;             // N*8
    float* ed1  = es1 + (size_t)NN * NH;              // N*8
    float* h2   = ed1 + (size_t)NN * NH;              // N*16
    u16*   w1t  = (u16*)h2;                           // 256*512 bf16 (256 KB < 3.2 MB)
    float* es2v = h2 + (size_t)NN * NC;               // N
    float* ed2v = es2v + NN;                          // N
    int* deg    = (int*)(ed2v + NN);                  // N
    int* cursor = deg + NN;                           // N
    int* offs   = cursor + NN;                        // N+1
    int* csr    = offs + NN + 1;                      // E

    hipMemsetAsync(deg, 0, NN * sizeof(int), stream);
    hipMemsetAsync(cursor, 0, NN * sizeof(int), stream);
    count_deg<<<(EE + 255) / 256, 256, 0, stream>>>(dstv, deg);
    scan_offsets<<<1, 1024, 0, stream>>>(deg, offs);
    fill_csr<<<(EE + 255) / 256, 256, 0, stream>>>(srcv, dstv, offs, cursor, csr);
    convert_x<<<((size_t)NN * KIN / 8 + 255) / 256, 256, 0, stream>>>(x, xb);
    convert_w1t<<<(KIN * HF) / 256, 256, 0, stream>>>(W1, w1t);
    gemm1_mfma<<<dim3((NN + 127) / 128, HF / 128), 256, 0, stream>>>(xb, w1t, h1);
    scores1<<<NN, 256, 0, stream>>>(h1, a1s, a1d, es1, ed1);
    agg1<<<NN, 256, 0, stream>>>(h1, es1, ed1, offs, csr, out1);
    gemm2<<<NN / 16, 256, 0, stream>>>(out1, W2, a2s, a2d, h2, es2v, ed2v);
    agg2<<<NN, 64, 0, stream>>>(h2, es2v, ed2v, offs, csr, out);
}

// Round 3
// 489.190 us; speedup vs baseline: 1.6643x; 1.2342x over previous
//
#include <hip/hip_runtime.h>

// Problem constants (from reference)
#define NN 50000
#define EE 800000
#define KIN 512
#define HF 256      // H*OUT
#define NH 8
#define FOUT 32
#define NC 16
#define NEG 0.2f
#define NB_SCAN 196  // ceil(NN/256)

typedef unsigned short u16;
typedef __attribute__((ext_vector_type(8))) short shortx8;   // 8 bf16 (4 VGPRs) MFMA A/B frag
typedef __attribute__((ext_vector_type(4))) float floatx4;   // MFMA C/D frag
typedef __attribute__((ext_vector_type(8))) unsigned short ushortx8;

__device__ __forceinline__ float lrelu(float x) { return x > 0.f ? x : NEG * x; }

__device__ __forceinline__ u16 f2bf(float f) {
    unsigned u = __float_as_uint(f);
    return (u16)((u + 0x7FFFu + ((u >> 16) & 1u)) >> 16);   // RNE
}
__device__ __forceinline__ float bf2f(u16 v) {
    return __uint_as_float((unsigned)v << 16);
}

__device__ __forceinline__ void gll16(const void* g, void* l) {
    // async global->LDS, 16B/lane; LDS dest = wave-uniform base + lane*16
    __builtin_amdgcn_global_load_lds((const __attribute__((address_space(1))) void*)g,
                                     (__attribute__((address_space(3))) void*)l, 16, 0, 0);
}

// ---------------- CSR build ----------------
__global__ void count_deg(const int* __restrict__ dst, int* __restrict__ deg) {
    int e = blockIdx.x * 256 + threadIdx.x;
    if (e < EE) atomicAdd(&deg[dst[e]], 1);
}

// hierarchical exclusive scan: per-block sums -> scan of sums -> per-block scan
__global__ __launch_bounds__(256) void scan_a(const int* __restrict__ deg, int* __restrict__ bsum) {
    __shared__ int sm[256];
    int t = threadIdx.x;
    int i = blockIdx.x * 256 + t;
    sm[t] = (i < NN) ? deg[i] : 0;
    __syncthreads();
    for (int o = 128; o; o >>= 1) { if (t < o) sm[t] += sm[t + o]; __syncthreads(); }
    if (t == 0) bsum[blockIdx.x] = sm[0];
}

__global__ __launch_bounds__(256) void scan_b(const int* __restrict__ bsum, int* __restrict__ boff) {
    __shared__ int sm[256];
    int t = threadIdx.x;
    sm[t] = (t < NB_SCAN) ? bsum[t] : 0;
    __syncthreads();
    for (int d = 1; d < 256; d <<= 1) {
        int v = (t >= d) ? sm[t - d] : 0;
        __syncthreads();
        sm[t] += v;
        __syncthreads();
    }
    if (t < NB_SCAN) boff[t] = (t == 0) ? 0 : sm[t - 1];
}

__global__ __launch_bounds__(256) void scan_c(const int* __restrict__ deg, const int* __restrict__ boff,
                                              int* __restrict__ off) {
    __shared__ int sm[256];
    int t = threadIdx.x;
    int i = blockIdx.x * 256 + t;
    int d = (i < NN) ? deg[i] : 0;
    sm[t] = d;
    __syncthreads();
    for (int dd = 1; dd < 256; dd <<= 1) {
        int v = (t >= dd) ? sm[t - dd] : 0;
        __syncthreads();
        sm[t] += v;
        __syncthreads();
    }
    if (i < NN) off[i] = boff[blockIdx.x] + sm[t] - d;   // exclusive prefix
    if (i == 0) off[NN] = EE;                            // total degree == E
}

__global__ void fill_csr(const int* __restrict__ src, const int* __restrict__ dst,
                         const int* __restrict__ off, int* __restrict__ cursor,
                         int* __restrict__ csr_src) {
    int e = blockIdx.x * 256 + threadIdx.x;
    if (e < EE) {
        int d = dst[e];
        int pos = atomicAdd(&cursor[d], 1);
        csr_src[off[d] + pos] = src[e];
    }
}

// ---------------- converts for bf16 GEMM1 ----------------
__global__ __launch_bounds__(256) void convert_x(const float* __restrict__ x, u16* __restrict__ xb) {
    size_t i = ((size_t)blockIdx.x * 256 + threadIdx.x) * 8;
    if (i >= (size_t)NN * KIN) return;
    float4 f0 = *(const float4*)(x + i);
    float4 f1 = *(const float4*)(x + i + 4);
    ushortx8 o;
    o[0] = f2bf(f0.x); o[1] = f2bf(f0.y); o[2] = f2bf(f0.z); o[3] = f2bf(f0.w);
    o[4] = f2bf(f1.x); o[5] = f2bf(f1.y); o[6] = f2bf(f1.z); o[7] = f2bf(f1.w);
    *(ushortx8*)(xb + i) = o;
}

// W1 [512,256] fp32 -> W1T [256,512] bf16
__global__ __launch_bounds__(256) void convert_w1t(const float* __restrict__ W1, u16* __restrict__ w1t) {
    int e = blockIdx.x * 256 + threadIdx.x;   // 512*256 = 131072
    int k = e >> 8, n = e & 255;
    w1t[n * KIN + k] = f2bf(W1[e]);
}

// ---------------- GEMM1 (bf16 MFMA): h1b[N,256] = xb[N,512] @ W1T^T ----------------
__global__ __launch_bounds__(256) void gemm1_mfma(const u16* __restrict__ xb,
                                                  const u16* __restrict__ w1t,
                                                  u16* __restrict__ h1b) {
    __shared__ __align__(16) u16 As[128 * 32];   // [row][k] 8 KB
    __shared__ __align__(16) u16 Bs[128 * 32];   // [col][k] 8 KB
    int t = threadIdx.x;
    int lane = t & 63, wave = t >> 6;
    int wm = wave >> 1, wn = wave & 1;
    int lm = lane & 15, quad = lane >> 4;
    int bm = blockIdx.x * 128;
    int bn = blockIdx.y * 128;

    floatx4 acc[4][4];
#pragma unroll
    for (int i = 0; i < 4; i++)
#pragma unroll
        for (int j = 0; j < 4; j++) acc[i][j] = (floatx4){0.f, 0.f, 0.f, 0.f};

    int sr = wave * 32 + (lane >> 2);
    int sk = (lane & 3) * 8;
    int ar0 = bm + sr, ar1 = ar0 + 16;
    if (ar0 > NN - 1) ar0 = NN - 1;
    if (ar1 > NN - 1) ar1 = NN - 1;
    const u16* agp0 = xb + (size_t)ar0 * KIN + sk;
    const u16* agp1 = xb + (size_t)ar1 * KIN + sk;
    const u16* bgp0 = w1t + (size_t)(bn + sr) * KIN + sk;
    const u16* bgp1 = w1t + (size_t)(bn + sr + 16) * KIN + sk;
    u16* asl0 = As + wave * 1024;
    u16* asl1 = As + wave * 1024 + 512;
    u16* bsl0 = Bs + wave * 1024;
    u16* bsl1 = Bs + wave * 1024 + 512;

    int offA[4], offB[4];
#pragma unroll
    for (int i = 0; i < 4; i++) offA[i] = (wm * 64 + i * 16 + lm) * 32 + quad * 8;
#pragma unroll
    for (int j = 0; j < 4; j++) offB[j] = (wn * 64 + j * 16 + lm) * 32 + quad * 8;

    for (int kk = 0; kk < KIN; kk += 32) {
        gll16(agp0 + kk, asl0);
        gll16(agp1 + kk, asl1);
        gll16(bgp0 + kk, bsl0);
        gll16(bgp1 + kk, bsl1);
        __syncthreads();
        shortx8 af[4], bf[4];
#pragma unroll
        for (int i = 0; i < 4; i++) af[i] = *(const shortx8*)&As[offA[i]];
#pragma unroll
        for (int j = 0; j < 4; j++) bf[j] = *(const shortx8*)&Bs[offB[j]];
#pragma unroll
        for (int i = 0; i < 4; i++)
#pragma unroll
            for (int j = 0; j < 4; j++)
                acc[i][j] = __builtin_amdgcn_mfma_f32_16x16x32_bf16(af[i], bf[j], acc[i][j], 0, 0, 0);
        __syncthreads();
    }

    // epilogue: C/D map col=lane&15, row=quad*4+reg -> write bf16
#pragma unroll
    for (int i = 0; i < 4; i++) {
        int row = bm + wm * 64 + i * 16 + quad * 4;
#pragma unroll
        for (int j = 0; j < 4; j++) {
            int col = bn + wn * 64 + j * 16 + lm;
#pragma unroll
            for (int r = 0; r < 4; r++) {
                if (row + r < NN) h1b[(size_t)(row + r) * HF + col] = f2bf(acc[i][j][r]);
            }
        }
    }
}

// ---------------- per-node attention scores layer 1 (bf16 h1) ----------------
__global__ __launch_bounds__(256) void scores1(const u16* __restrict__ h1b, const float* __restrict__ a_src,
                                               const float* __restrict__ a_dst,
                                               float* __restrict__ es, float* __restrict__ ed) {
    int n = blockIdx.x, t = threadIdx.x;
    float v = bf2f(h1b[(size_t)n * HF + t]);
    float ps = v * a_src[t];
    float pd = v * a_dst[t];
#pragma unroll
    for (int o = 16; o; o >>= 1) {
        ps += __shfl_down(ps, o, 32);
        pd += __shfl_down(pd, o, 32);
    }
    if ((t & 31) == 0) {
        es[n * NH + (t >> 5)] = ps;
        ed[n * NH + (t >> 5)] = pd;
    }
}

// ---------------- layer-1 online-softmax aggregate (+ ELU), block = 1 dst node ----------------
__global__ __launch_bounds__(256) void agg1(const u16* __restrict__ h1b, const float* __restrict__ es,
                                            const float* __restrict__ ed, const int* __restrict__ off,
                                            const int* __restrict__ csr_src, u16* __restrict__ out1b) {
    int n = blockIdx.x, t = threadIdx.x;
    __shared__ float edl[NH];
    __shared__ float p_chunk[32][9];   // +1 pad: write pattern el*9+h conflict-free
    __shared__ int src_chunk[32];
    int beg = off[n];
    int deg = off[n + 1] - beg;
    if (t < NH) edl[t] = ed[n * NH + t];
    int h = t >> 5;    // head for this feature (t is the feature index)
    int el = t & 31;   // edge slot within chunk
    float m_run = -3.0e38f, s_run = 0.f, acc = 0.f;
    __syncthreads();
    float edh = edl[h];
    for (int base = 0; base < deg; base += 32) {
        int nch = deg - base; if (nch > 32) nch = 32;
        if (t < nch) src_chunk[t] = csr_src[beg + base + t];
        __syncthreads();
        // per-(head,slot) logit; online-softmax chunk update
        float v = -3.0e38f;
        if (el < nch) v = lrelu(es[src_chunk[el] * NH + h] + edh);
        float cm = v;
#pragma unroll
        for (int o = 16; o; o >>= 1) cm = fmaxf(cm, __shfl_down(cm, o, 32));
        cm = __shfl(cm, 0, 32);
        float m_new = fmaxf(m_run, cm);
        float sc = __expf(m_run - m_new);
        float p = (el < nch) ? __expf(v - m_new) : 0.f;
        float ps = p;
#pragma unroll
        for (int o = 16; o; o >>= 1) ps += __shfl_down(ps, o, 32);
        ps = __shfl(ps, 0, 32);
        s_run = s_run * sc + ps;
        acc *= sc;
        m_run = m_new;
        p_chunk[el][h] = p;   // read back only within the same 32-lane group (intra-wave, no barrier)
#pragma unroll 4
        for (int e2 = 0; e2 < nch; e2++) {
            float hv = bf2f(h1b[(size_t)src_chunk[e2] * HF + t]);
            acc += p_chunk[e2][h] * hv;
        }
        __syncthreads();   // before next chunk overwrites src_chunk
    }
    float inv_s = s_run > 0.f ? 1.0f / s_run : 0.f;
    float vv = acc * inv_s;
    out1b[(size_t)n * HF + t] = f2bf(vv > 0.f ? vv : (__expf(vv) - 1.0f));  // fused ELU
}

// ---------------- GEMM2 + layer-2 scores (bf16 out1) ----------------
__global__ __launch_bounds__(256) void gemm2(const u16* __restrict__ out1b, const float* __restrict__ W2,
                                             const float* __restrict__ a2s, const float* __restrict__ a2d,
                                             float* __restrict__ h2, float* __restrict__ es2,
                                             float* __restrict__ ed2) {
    __shared__ float rows[16][257];   // +1 pad
    __shared__ float w[256][16];
    int t = threadIdx.x;
    int nb = blockIdx.x * 16;
    for (int i = t; i < 256 * 16; i += 256) ((float*)w)[i] = W2[i];
    for (int r = 0; r < 16; r++) rows[r][t] = bf2f(out1b[(size_t)(nb + r) * HF + t]);
    __syncthreads();
    int nl = t >> 4, c = t & 15;
    float acc = 0.f;
#pragma unroll 8
    for (int k = 0; k < 256; k++) acc += rows[nl][k] * w[k][c];
    int n = nb + nl;
    h2[n * NC + c] = acc;
    float ps = acc * a2s[c];
    float pd = acc * a2d[c];
#pragma unroll
    for (int o = 8; o; o >>= 1) {
        ps += __shfl_down(ps, o, 16);
        pd += __shfl_down(pd, o, 16);
    }
    if (c == 0) { es2[n] = ps; ed2[n] = pd; }
}

// ---------------- layer-2 online-softmax aggregate + log_softmax ----------------
// 256 threads = 16 nodes x 16 classes
__global__ __launch_bounds__(256) void agg2(const float* __restrict__ h2, const float* __restrict__ es2,
                                            const float* __restrict__ ed2, const int* __restrict__ off,
                                            const int* __restrict__ csr_src, float* __restrict__ out) {
    int t = threadIdx.x;
    int nid = blockIdx.x * 16 + (t >> 4);   // NN % 16 == 0 -> no guard
    int c = t & 15;
    int beg = off[nid];
    int deg = off[nid + 1] - beg;
    float edn = ed2[nid];
    float m = -3.0e38f, s = 0.f, acc = 0.f;
    for (int e = 0; e < deg; e++) {
        int sv = csr_src[beg + e];          // broadcast across the 16 lanes of this node
        float ev = lrelu(es2[sv] + edn);
        float mn = fmaxf(m, ev);
        float sc = __expf(m - mn);
        float p = __expf(ev - mn);
        acc = acc * sc + p * h2[sv * NC + c];
        s = s * sc + p;
        m = mn;
    }
    float v = (s > 0.f) ? acc / s : 0.f;
    float m2 = v;
#pragma unroll
    for (int o = 8; o; o >>= 1) m2 = fmaxf(m2, __shfl_down(m2, o, 16));
    m2 = __shfl(m2, 0, 16);
    float se = __expf(v - m2);
#pragma unroll
    for (int o = 8; o; o >>= 1) se += __shfl_down(se, o, 16);
    se = __shfl(se, 0, 16);
    out[nid * NC + c] = v - m2 - __logf(se);
}

extern "C" void kernel_launch(void* const* d_in, const int* in_sizes, int n_in,
                              void* d_out, int out_size, void* d_ws, size_t ws_size,
                              hipStream_t stream) {
    const float* x   = (const float*)d_in[0];
    const float* W1  = (const float*)d_in[1];
    const float* a1s = (const float*)d_in[2];
    const float* a1d = (const float*)d_in[3];
    const float* W2  = (const float*)d_in[4];
    const float* a2s = (const float*)d_in[5];
    const float* a2d = (const float*)d_in[6];
    const int*   ei  = (const int*)d_in[7];
    const int* srcv = ei;
    const int* dstv = ei + EE;
    float* out = (float*)d_out;

    // workspace (~88 MB): out1b aliases xb (xb dead after gemm1); w1t aliases h2
    u16* h1b   = (u16*)d_ws;                          // N*256 bf16 (25.6 MB)
    u16* xb    = h1b + (size_t)NN * HF;               // N*512 bf16 (51.2 MB)
    u16* out1b = xb;                                  // N*256 bf16, alias
    float* es1 = (float*)(xb + (size_t)NN * KIN);     // N*8
    float* ed1 = es1 + (size_t)NN * NH;               // N*8
    float* h2  = ed1 + (size_t)NN * NH;               // N*16
    u16* w1t   = (u16*)h2;                            // 256*512 bf16 (256 KB), dead before gemm2
    float* es2v = h2 + (size_t)NN * NC;               // N
    float* ed2v = es2v + NN;                          // N
    int* deg    = (int*)(ed2v + NN);                  // N
    int* cursor = deg + NN;                           // N
    int* offs   = cursor + NN;                        // N+1
    int* csr    = offs + NN + 1;                      // E
    int* bsum   = csr + EE;                           // 256
    int* boff   = bsum + 256;                         // 256

    hipMemsetAsync(deg, 0, NN * sizeof(int), stream);
    hipMemsetAsync(cursor, 0, NN * sizeof(int), stream);
    count_deg<<<(EE + 255) / 256, 256, 0, stream>>>(dstv, deg);
    scan_a<<<NB_SCAN, 256, 0, stream>>>(deg, bsum);
    scan_b<<<1, 256, 0, stream>>>(bsum, boff);
    scan_c<<<NB_SCAN, 256, 0, stream>>>(deg, boff, offs);
    fill_csr<<<(EE + 255) / 256, 256, 0, stream>>>(srcv, dstv, offs, cursor, csr);
    convert_x<<<((size_t)NN * KIN / 8 + 255) / 256, 256, 0, stream>>>(x, xb);
    convert_w1t<<<(KIN * HF) / 256, 256, 0, stream>>>(W1, w1t);
    gemm1_mfma<<<dim3((NN + 127) / 128, HF / 128), 256, 0, stream>>>(xb, w1t, h1b);
    scores1<<<NN, 256, 0, stream>>>(h1b, a1s, a1d, es1, ed1);
    agg1<<<NN, 256, 0, stream>>>(h1b, es1, ed1, offs, csr, out1b);
    gemm2<<<NN / 16, 256, 0, stream>>>(out1b, W2, a2s, a2d, h2, es2v, ed2v);
    agg2<<<NN / 16, 256, 0, stream>>>(h2, es2v, ed2v, offs, csr, out);
}

// Round 4
// 432.953 us; speedup vs baseline: 1.8805x; 1.1299x over previous
//
#include <hip/hip_runtime.h>

// Problem constants (from reference)
#define NN 50000
#define EE 800000
#define KIN 512
#define HF 256      // H*OUT
#define NH 8
#define FOUT 32
#define NC 16
#define NEG 0.2f
#define NB_SCAN 196  // ceil(NN/256)

typedef unsigned short u16;
typedef __attribute__((ext_vector_type(8))) short shortx8;   // 8 bf16 (4 VGPRs) MFMA A/B frag
typedef __attribute__((ext_vector_type(4))) float floatx4;   // MFMA C/D frag
typedef __attribute__((ext_vector_type(8))) unsigned short ushortx8;
typedef __attribute__((ext_vector_type(4))) unsigned short ushortx4;

__device__ __forceinline__ float lrelu(float x) { return x > 0.f ? x : NEG * x; }

__device__ __forceinline__ u16 f2bf(float f) {
    unsigned u = __float_as_uint(f);
    return (u16)((u + 0x7FFFu + ((u >> 16) & 1u)) >> 16);   // RNE
}
__device__ __forceinline__ float bf2f(u16 v) {
    return __uint_as_float((unsigned)v << 16);
}

__device__ __forceinline__ void gll16(const void* g, void* l) {
    // async global->LDS, 16B/lane; LDS dest = wave-uniform base + lane*16
    __builtin_amdgcn_global_load_lds((const __attribute__((address_space(1))) void*)g,
                                     (__attribute__((address_space(3))) void*)l, 16, 0, 0);
}

// ---------------- CSR build ----------------
__global__ void count_deg(const int* __restrict__ dst, int* __restrict__ deg) {
    int e = blockIdx.x * 256 + threadIdx.x;
    if (e < EE) atomicAdd(&deg[dst[e]], 1);
}

__global__ __launch_bounds__(256) void scan_a(const int* __restrict__ deg, int* __restrict__ bsum) {
    __shared__ int sm[256];
    int t = threadIdx.x;
    int i = blockIdx.x * 256 + t;
    sm[t] = (i < NN) ? deg[i] : 0;
    __syncthreads();
    for (int o = 128; o; o >>= 1) { if (t < o) sm[t] += sm[t + o]; __syncthreads(); }
    if (t == 0) bsum[blockIdx.x] = sm[0];
}

__global__ __launch_bounds__(256) void scan_b(const int* __restrict__ bsum, int* __restrict__ boff) {
    __shared__ int sm[256];
    int t = threadIdx.x;
    sm[t] = (t < NB_SCAN) ? bsum[t] : 0;
    __syncthreads();
    for (int d = 1; d < 256; d <<= 1) {
        int v = (t >= d) ? sm[t - d] : 0;
        __syncthreads();
        sm[t] += v;
        __syncthreads();
    }
    if (t < NB_SCAN) boff[t] = (t == 0) ? 0 : sm[t - 1];
}

__global__ __launch_bounds__(256) void scan_c(const int* __restrict__ deg, const int* __restrict__ boff,
                                              int* __restrict__ off) {
    __shared__ int sm[256];
    int t = threadIdx.x;
    int i = blockIdx.x * 256 + t;
    int d = (i < NN) ? deg[i] : 0;
    sm[t] = d;
    __syncthreads();
    for (int dd = 1; dd < 256; dd <<= 1) {
        int v = (t >= dd) ? sm[t - dd] : 0;
        __syncthreads();
        sm[t] += v;
        __syncthreads();
    }
    if (i < NN) off[i] = boff[blockIdx.x] + sm[t] - d;
    if (i == 0) off[NN] = EE;
}

__global__ void fill_csr(const int* __restrict__ src, const int* __restrict__ dst,
                         const int* __restrict__ off, int* __restrict__ cursor,
                         int* __restrict__ csr_src) {
    int e = blockIdx.x * 256 + threadIdx.x;
    if (e < EE) {
        int d = dst[e];
        int pos = atomicAdd(&cursor[d], 1);
        csr_src[off[d] + pos] = src[e];
    }
}

// ---------------- converts ----------------
__global__ __launch_bounds__(256) void convert_x(const float* __restrict__ x, u16* __restrict__ xb) {
    size_t i = ((size_t)blockIdx.x * 256 + threadIdx.x) * 8;
    if (i >= (size_t)NN * KIN) return;
    float4 f0 = *(const float4*)(x + i);
    float4 f1 = *(const float4*)(x + i + 4);
    ushortx8 o;
    o[0] = f2bf(f0.x); o[1] = f2bf(f0.y); o[2] = f2bf(f0.z); o[3] = f2bf(f0.w);
    o[4] = f2bf(f1.x); o[5] = f2bf(f1.y); o[6] = f2bf(f1.z); o[7] = f2bf(f1.w);
    *(ushortx8*)(xb + i) = o;
}

// W1 [512,256] fp32 -> W1T [256,512] bf16
__global__ __launch_bounds__(256) void convert_w1t(const float* __restrict__ W1, u16* __restrict__ w1t) {
    int e = blockIdx.x * 256 + threadIdx.x;
    int k = e >> 8, n = e & 255;
    w1t[n * KIN + k] = f2bf(W1[e]);
}

// W2 [256,16] fp32 -> W2T [16,256] bf16
__global__ __launch_bounds__(256) void convert_w2t(const float* __restrict__ W2, u16* __restrict__ w2t) {
    int e = blockIdx.x * 256 + threadIdx.x;   // 4096
    int k = e >> 4, c = e & 15;
    w2t[c * HF + k] = f2bf(W2[e]);
}

// ---------------- GEMM1 (bf16 MFMA): h1b[N,256] = xb[N,512] @ W1T^T ----------------
__global__ __launch_bounds__(256) void gemm1_mfma(const u16* __restrict__ xb,
                                                  const u16* __restrict__ w1t,
                                                  u16* __restrict__ h1b) {
    __shared__ __align__(16) u16 As[128 * 32];
    __shared__ __align__(16) u16 Bs[128 * 32];
    int t = threadIdx.x;
    int lane = t & 63, wave = t >> 6;
    int wm = wave >> 1, wn = wave & 1;
    int lm = lane & 15, quad = lane >> 4;
    int bm = blockIdx.x * 128;
    int bn = blockIdx.y * 128;

    floatx4 acc[4][4];
#pragma unroll
    for (int i = 0; i < 4; i++)
#pragma unroll
        for (int j = 0; j < 4; j++) acc[i][j] = (floatx4){0.f, 0.f, 0.f, 0.f};

    int sr = wave * 32 + (lane >> 2);
    int sk = (lane & 3) * 8;
    int ar0 = bm + sr, ar1 = ar0 + 16;
    if (ar0 > NN - 1) ar0 = NN - 1;
    if (ar1 > NN - 1) ar1 = NN - 1;
    const u16* agp0 = xb + (size_t)ar0 * KIN + sk;
    const u16* agp1 = xb + (size_t)ar1 * KIN + sk;
    const u16* bgp0 = w1t + (size_t)(bn + sr) * KIN + sk;
    const u16* bgp1 = w1t + (size_t)(bn + sr + 16) * KIN + sk;
    u16* asl0 = As + wave * 1024;
    u16* asl1 = As + wave * 1024 + 512;
    u16* bsl0 = Bs + wave * 1024;
    u16* bsl1 = Bs + wave * 1024 + 512;

    int offA[4], offB[4];
#pragma unroll
    for (int i = 0; i < 4; i++) offA[i] = (wm * 64 + i * 16 + lm) * 32 + quad * 8;
#pragma unroll
    for (int j = 0; j < 4; j++) offB[j] = (wn * 64 + j * 16 + lm) * 32 + quad * 8;

    for (int kk = 0; kk < KIN; kk += 32) {
        gll16(agp0 + kk, asl0);
        gll16(agp1 + kk, asl1);
        gll16(bgp0 + kk, bsl0);
        gll16(bgp1 + kk, bsl1);
        __syncthreads();
        shortx8 af[4], bf[4];
#pragma unroll
        for (int i = 0; i < 4; i++) af[i] = *(const shortx8*)&As[offA[i]];
#pragma unroll
        for (int j = 0; j < 4; j++) bf[j] = *(const shortx8*)&Bs[offB[j]];
#pragma unroll
        for (int i = 0; i < 4; i++)
#pragma unroll
            for (int j = 0; j < 4; j++)
                acc[i][j] = __builtin_amdgcn_mfma_f32_16x16x32_bf16(af[i], bf[j], acc[i][j], 0, 0, 0);
        __syncthreads();
    }

#pragma unroll
    for (int i = 0; i < 4; i++) {
        int row = bm + wm * 64 + i * 16 + quad * 4;
#pragma unroll
        for (int j = 0; j < 4; j++) {
            int col = bn + wn * 64 + j * 16 + lm;
#pragma unroll
            for (int r = 0; r < 4; r++) {
                if (row + r < NN) h1b[(size_t)(row + r) * HF + col] = f2bf(acc[i][j][r]);
            }
        }
    }
}

// ---------------- per-node attention scores layer 1: 8 nodes/block, 16B loads ----------------
__global__ __launch_bounds__(256) void scores1(const u16* __restrict__ h1b, const float* __restrict__ a_src,
                                               const float* __restrict__ a_dst,
                                               float* __restrict__ es, float* __restrict__ ed) {
    __shared__ float as_s[HF], ad_s[HF];
    int t = threadIdx.x;
    as_s[t] = a_src[t];
    ad_s[t] = a_dst[t];
    __syncthreads();
    int nl = t >> 5;              // node slot 0..7
    int L = t & 31;               // lane: features 8L..8L+7 (one head: h = L>>2)
    int n = blockIdx.x * 8 + nl;  // NN % 8 == 0
    ushortx8 hv = *(const ushortx8*)(h1b + (size_t)n * HF + L * 8);
    float ps = 0.f, pd = 0.f;
#pragma unroll
    for (int i = 0; i < 8; i++) {
        float v = bf2f(hv[i]);
        ps += v * as_s[L * 8 + i];
        pd += v * ad_s[L * 8 + i];
    }
    ps += __shfl_down(ps, 2, 4); ps += __shfl_down(ps, 1, 4);
    pd += __shfl_down(pd, 2, 4); pd += __shfl_down(pd, 1, 4);
    if ((L & 3) == 0) {
        int h = L >> 2;
        es[n * NH + h] = ps;
        ed[n * NH + h] = pd;
    }
}

// ---------------- layer-1 online-softmax aggregate (+ ELU), block = 1 dst node ----------------
// 256 threads = 64 feature-lanes (4 features each, ushort4 loads) x 4 edge-slots
__global__ __launch_bounds__(256) void agg1(const u16* __restrict__ h1b, const float* __restrict__ es,
                                            const float* __restrict__ ed, const int* __restrict__ off,
                                            const int* __restrict__ csr_src, u16* __restrict__ out1b) {
    int n = blockIdx.x, t = threadIdx.x;
    __shared__ float edl[NH];
    __shared__ float p_chunk[32][9];    // +1 pad
    __shared__ float sc_h[NH], s_h[NH];
    __shared__ int src_chunk[32];
    __shared__ float red[4][HF];        // per-wave partial accumulators
    int beg = off[n];
    int deg = off[n + 1] - beg;
    if (t < NH) edl[t] = ed[n * NH + t];
    // p-compute role: head ph, edge-slot el
    int ph = t >> 5, el = t & 31;
    // aggregation role: wave w handles edges w, w+4, ...; lane L owns features 4L..4L+3
    int w = t >> 6, L = t & 63;
    int ah = L >> 3;                    // head of features 4L..4L+3
    float m_run = -3.0e38f, s_run = 0.f;
    float acc0 = 0.f, acc1 = 0.f, acc2 = 0.f, acc3 = 0.f;
    __syncthreads();
    float edh = edl[ph];
    for (int base = 0; base < deg; base += 32) {
        int nch = deg - base; if (nch > 32) nch = 32;
        if (t < nch) src_chunk[t] = csr_src[beg + base + t];
        __syncthreads();
        // online-softmax chunk update (per head, 32 lanes each)
        float v = -3.0e38f;
        if (el < nch) v = lrelu(es[src_chunk[el] * NH + ph] + edh);
        float cm = v;
#pragma unroll
        for (int o = 16; o; o >>= 1) cm = fmaxf(cm, __shfl_down(cm, o, 32));
        cm = __shfl(cm, 0, 32);
        float m_new = fmaxf(m_run, cm);
        float sc = __expf(m_run - m_new);
        float p = (el < nch) ? __expf(v - m_new) : 0.f;
        float ps = p;
#pragma unroll
        for (int o = 16; o; o >>= 1) ps += __shfl_down(ps, o, 32);
        ps = __shfl(ps, 0, 32);
        s_run = s_run * sc + ps;
        m_run = m_new;
        p_chunk[el][ph] = p;
        if (el == 0) sc_h[ph] = sc;
        __syncthreads();
        // aggregation: each wave covers a subset of edges across all 256 features
        float scl = sc_h[ah];
        acc0 *= scl; acc1 *= scl; acc2 *= scl; acc3 *= scl;
        for (int e = w; e < nch; e += 4) {
            float p2 = p_chunk[e][ah];
            ushortx4 hv = *(const ushortx4*)(h1b + (size_t)src_chunk[e] * HF + L * 4);
            acc0 += p2 * bf2f(hv[0]);
            acc1 += p2 * bf2f(hv[1]);
            acc2 += p2 * bf2f(hv[2]);
            acc3 += p2 * bf2f(hv[3]);
        }
        __syncthreads();   // protect src_chunk/p_chunk/sc_h before next chunk
    }
    if (el == 0) s_h[ph] = s_run;
    *(float4*)&red[w][L * 4] = make_float4(acc0, acc1, acc2, acc3);
    __syncthreads();
    // cross-wave reduce; thread t owns feature t
    float vv = red[0][t] + red[1][t] + red[2][t] + red[3][t];
    float sh = s_h[t >> 5];
    vv *= (sh > 0.f ? 1.0f / sh : 0.f);
    out1b[(size_t)n * HF + t] = f2bf(vv > 0.f ? vv : (__expf(vv) - 1.0f));  // fused ELU
}

// ---------------- GEMM2 (1-wave MFMA) + layer-2 scores ----------------
// block = 64 threads = 1 wave; 16 nodes; K=256 -> 8 MFMA 16x16x32, direct global frags
__global__ __launch_bounds__(64) void gemm2_mfma(const u16* __restrict__ out1b, const u16* __restrict__ w2t,
                                                 const float* __restrict__ a2s, const float* __restrict__ a2d,
                                                 float* __restrict__ h2, float* __restrict__ es2,
                                                 float* __restrict__ ed2) {
    int lane = threadIdx.x;
    int lm = lane & 15, quad = lane >> 4;
    int nb = blockIdx.x * 16;
    floatx4 acc = (floatx4){0.f, 0.f, 0.f, 0.f};
    const u16* arow = out1b + (size_t)(nb + lm) * HF + quad * 8;   // A[m=lm][k=quad*8+j]
    const u16* brow = w2t + lm * HF + quad * 8;                    // B[n=lm][k=quad*8+j]
#pragma unroll
    for (int kk = 0; kk < HF; kk += 32) {
        shortx8 af = *(const shortx8*)(arow + kk);
        shortx8 bf = *(const shortx8*)(brow + kk);
        acc = __builtin_amdgcn_mfma_f32_16x16x32_bf16(af, bf, acc, 0, 0, 0);
    }
    // C/D: col(class)=lm, row(node)=quad*4+r
    float a2sc = a2s[lm], a2dc = a2d[lm];
#pragma unroll
    for (int r = 0; r < 4; r++) {
        int n = nb + quad * 4 + r;
        float v = acc[r];
        h2[n * NC + lm] = v;
        float ps = v * a2sc, pd = v * a2dc;
#pragma unroll
        for (int o = 8; o; o >>= 1) {
            ps += __shfl_down(ps, o, 16);
            pd += __shfl_down(pd, o, 16);
        }
        if (lm == 0) { es2[n] = ps; ed2[n] = pd; }
    }
}

// ---------------- layer-2 aggregate + log_softmax: 16 nodes x 16 classes, chunk-parallel ----------------
__global__ __launch_bounds__(256) void agg2(const float* __restrict__ h2, const float* __restrict__ es2,
                                            const float* __restrict__ ed2, const int* __restrict__ off,
                                            const int* __restrict__ csr_src, float* __restrict__ out) {
    int t = threadIdx.x;
    int nid = blockIdx.x * 16 + (t >> 4);   // NN % 16 == 0
    int c = t & 15;
    int beg = off[nid];
    int deg = off[nid + 1] - beg;
    float edn = ed2[nid];
    float m = -3.0e38f, s = 0.f, acc = 0.f;
    for (int base = 0; base < deg; base += 16) {
        int nch = deg - base; if (nch > 16) nch = 16;
        // lane c scores edge (base+c) in parallel
        int sv = 0; float ev = -3.0e38f;
        if (c < nch) {
            sv = csr_src[beg + base + c];
            ev = lrelu(es2[sv] + edn);
        }
        float cm = ev;
#pragma unroll
        for (int o = 8; o; o >>= 1) cm = fmaxf(cm, __shfl_down(cm, o, 16));
        cm = __shfl(cm, 0, 16);
        float mn = fmaxf(m, cm);
        float scl = __expf(m - mn);
        float p = (c < nch) ? __expf(ev - mn) : 0.f;
        float psum = p;
#pragma unroll
        for (int o = 8; o; o >>= 1) psum += __shfl_down(psum, o, 16);
        psum = __shfl(psum, 0, 16);
        s = s * scl + psum;
        acc *= scl;
        m = mn;
        for (int e = 0; e < nch; e++) {
            int sve = __shfl(sv, e, 16);
            float pe = __shfl(p, e, 16);
            acc += pe * h2[sve * NC + c];
        }
    }
    float v = (s > 0.f) ? acc / s : 0.f;
    float m2 = v;
#pragma unroll
    for (int o = 8; o; o >>= 1) m2 = fmaxf(m2, __shfl_down(m2, o, 16));
    m2 = __shfl(m2, 0, 16);
    float se = __expf(v - m2);
#pragma unroll
    for (int o = 8; o; o >>= 1) se += __shfl_down(se, o, 16);
    se = __shfl(se, 0, 16);
    out[nid * NC + c] = v - m2 - __logf(se);
}

extern "C" void kernel_launch(void* const* d_in, const int* in_sizes, int n_in,
                              void* d_out, int out_size, void* d_ws, size_t ws_size,
                              hipStream_t stream) {
    const float* x   = (const float*)d_in[0];
    const float* W1  = (const float*)d_in[1];
    const float* a1s = (const float*)d_in[2];
    const float* a1d = (const float*)d_in[3];
    const float* W2  = (const float*)d_in[4];
    const float* a2s = (const float*)d_in[5];
    const float* a2d = (const float*)d_in[6];
    const int*   ei  = (const int*)d_in[7];
    const int* srcv = ei;
    const int* dstv = ei + EE;
    float* out = (float*)d_out;

    // workspace (~88 MB): out1b aliases xb (xb dead after gemm1); w1t aliases h2
    u16* h1b   = (u16*)d_ws;                          // N*256 bf16 (25.6 MB)
    u16* xb    = h1b + (size_t)NN * HF;               // N*512 bf16 (51.2 MB)
    u16* out1b = xb;                                  // N*256 bf16, alias
    float* es1 = (float*)(xb + (size_t)NN * KIN);     // N*8
    float* ed1 = es1 + (size_t)NN * NH;               // N*8
    float* h2  = ed1 + (size_t)NN * NH;               // N*16
    u16* w1t   = (u16*)h2;                            // 256*512 bf16, dead before gemm2
    float* es2v = h2 + (size_t)NN * NC;               // N
    float* ed2v = es2v + NN;                          // N
    int* deg    = (int*)(ed2v + NN);                  // N
    int* cursor = deg + NN;                           // N
    int* offs   = cursor + NN;                        // N+1
    int* csr    = offs + NN + 1;                      // E
    int* bsum   = csr + EE;                           // 256
    int* boff   = bsum + 256;                         // 256
    u16* w2t    = (u16*)(boff + 256);                 // 16*256 bf16 (8 KB)

    hipMemsetAsync(deg, 0, NN * sizeof(int), stream);
    hipMemsetAsync(cursor, 0, NN * sizeof(int), stream);
    count_deg<<<(EE + 255) / 256, 256, 0, stream>>>(dstv, deg);
    scan_a<<<NB_SCAN, 256, 0, stream>>>(deg, bsum);
    scan_b<<<1, 256, 0, stream>>>(bsum, boff);
    scan_c<<<NB_SCAN, 256, 0, stream>>>(deg, boff, offs);
    fill_csr<<<(EE + 255) / 256, 256, 0, stream>>>(srcv, dstv, offs, cursor, csr);
    convert_x<<<((size_t)NN * KIN / 8 + 255) / 256, 256, 0, stream>>>(x, xb);
    convert_w1t<<<(KIN * HF) / 256, 256, 0, stream>>>(W1, w1t);
    convert_w2t<<<(HF * NC) / 256, 256, 0, stream>>>(W2, w2t);
    gemm1_mfma<<<dim3((NN + 127) / 128, HF / 128), 256, 0, stream>>>(xb, w1t, h1b);
    scores1<<<NN / 8, 256, 0, stream>>>(h1b, a1s, a1d, es1, ed1);
    agg1<<<NN, 256, 0, stream>>>(h1b, es1, ed1, offs, csr, out1b);
    gemm2_mfma<<<NN / 16, 64, 0, stream>>>(out1b, w2t, a2s, a2d, h2, es2v, ed2v);
    agg2<<<NN / 16, 256, 0, stream>>>(h2, es2v, ed2v, offs, csr, out);
}

// Round 5
// 424.633 us; speedup vs baseline: 1.9173x; 1.0196x over previous
//
#include <hip/hip_runtime.h>

// Problem constants (from reference)
#define NN 50000
#define EE 800000
#define KIN 512
#define HF 256      // H*OUT
#define NH 8
#define FOUT 32
#define NC 16
#define NEG 0.2f
#define NB_SCAN 196  // ceil(NN/256)

typedef unsigned short u16;
typedef __attribute__((ext_vector_type(8))) short shortx8;   // 8 bf16 (4 VGPRs) MFMA A/B frag
typedef __attribute__((ext_vector_type(4))) float floatx4;   // MFMA C/D frag
typedef __attribute__((ext_vector_type(8))) unsigned short ushortx8;
typedef __attribute__((ext_vector_type(4))) unsigned short ushortx4;

__device__ __forceinline__ float lrelu(float x) { return x > 0.f ? x : NEG * x; }

__device__ __forceinline__ u16 f2bf(float f) {
    unsigned u = __float_as_uint(f);
    return (u16)((u + 0x7FFFu + ((u >> 16) & 1u)) >> 16);   // RNE
}
__device__ __forceinline__ float bf2f(u16 v) {
    return __uint_as_float((unsigned)v << 16);
}

__device__ __forceinline__ void gll16(const void* g, void* l) {
    __builtin_amdgcn_global_load_lds((const __attribute__((address_space(1))) void*)g,
                                     (__attribute__((address_space(3))) void*)l, 16, 0, 0);
}

// ---------------- CSR build ----------------
__global__ void count_deg(const int* __restrict__ dst, int* __restrict__ deg) {
    int e = blockIdx.x * 256 + threadIdx.x;
    if (e < EE) atomicAdd(&deg[dst[e]], 1);
}

__global__ __launch_bounds__(256) void scan_a(const int* __restrict__ deg, int* __restrict__ bsum) {
    __shared__ int sm[256];
    int t = threadIdx.x;
    int i = blockIdx.x * 256 + t;
    sm[t] = (i < NN) ? deg[i] : 0;
    __syncthreads();
    for (int o = 128; o; o >>= 1) { if (t < o) sm[t] += sm[t + o]; __syncthreads(); }
    if (t == 0) bsum[blockIdx.x] = sm[0];
}

__global__ __launch_bounds__(256) void scan_b(const int* __restrict__ bsum, int* __restrict__ boff) {
    __shared__ int sm[256];
    int t = threadIdx.x;
    sm[t] = (t < NB_SCAN) ? bsum[t] : 0;
    __syncthreads();
    for (int d = 1; d < 256; d <<= 1) {
        int v = (t >= d) ? sm[t - d] : 0;
        __syncthreads();
        sm[t] += v;
        __syncthreads();
    }
    if (t < NB_SCAN) boff[t] = (t == 0) ? 0 : sm[t - 1];
}

__global__ __launch_bounds__(256) void scan_c(const int* __restrict__ deg, const int* __restrict__ boff,
                                              int* __restrict__ off) {
    __shared__ int sm[256];
    int t = threadIdx.x;
    int i = blockIdx.x * 256 + t;
    int d = (i < NN) ? deg[i] : 0;
    sm[t] = d;
    __syncthreads();
    for (int dd = 1; dd < 256; dd <<= 1) {
        int v = (t >= dd) ? sm[t - dd] : 0;
        __syncthreads();
        sm[t] += v;
        __syncthreads();
    }
    if (i < NN) off[i] = boff[blockIdx.x] + sm[t] - d;
    if (i == 0) off[NN] = EE;
}

__global__ void fill_csr(const int* __restrict__ src, const int* __restrict__ dst,
                         const int* __restrict__ off, int* __restrict__ cursor,
                         int* __restrict__ csr_src) {
    int e = blockIdx.x * 256 + threadIdx.x;
    if (e < EE) {
        int d = dst[e];
        int pos = atomicAdd(&cursor[d], 1);
        csr_src[off[d] + pos] = src[e];
    }
}

// ---------------- converts ----------------
__global__ __launch_bounds__(256) void convert_x(const float* __restrict__ x, u16* __restrict__ xb) {
    size_t i = ((size_t)blockIdx.x * 256 + threadIdx.x) * 8;
    if (i >= (size_t)NN * KIN) return;
    float4 f0 = *(const float4*)(x + i);
    float4 f1 = *(const float4*)(x + i + 4);
    ushortx8 o;
    o[0] = f2bf(f0.x); o[1] = f2bf(f0.y); o[2] = f2bf(f0.z); o[3] = f2bf(f0.w);
    o[4] = f2bf(f1.x); o[5] = f2bf(f1.y); o[6] = f2bf(f1.z); o[7] = f2bf(f1.w);
    *(ushortx8*)(xb + i) = o;
}

// W1 [512,256] fp32 -> W1T [256,512] bf16
__global__ __launch_bounds__(256) void convert_w1t(const float* __restrict__ W1, u16* __restrict__ w1t) {
    int e = blockIdx.x * 256 + threadIdx.x;
    int k = e >> 8, n = e & 255;
    w1t[n * KIN + k] = f2bf(W1[e]);
}

// W2 [256,16] fp32 -> W2T [16,256] bf16
__global__ __launch_bounds__(256) void convert_w2t(const float* __restrict__ W2, u16* __restrict__ w2t) {
    int e = blockIdx.x * 256 + threadIdx.x;   // 4096
    int k = e >> 4, c = e & 15;
    w2t[c * HF + k] = f2bf(W2[e]);
}

// ---------------- GEMM1 (bf16 MFMA): h1b[N,256] = xb[N,512] @ W1T^T ----------------
__global__ __launch_bounds__(256) void gemm1_mfma(const u16* __restrict__ xb,
                                                  const u16* __restrict__ w1t,
                                                  u16* __restrict__ h1b) {
    __shared__ __align__(16) u16 As[128 * 32];
    __shared__ __align__(16) u16 Bs[128 * 32];
    int t = threadIdx.x;
    int lane = t & 63, wave = t >> 6;
    int wm = wave >> 1, wn = wave & 1;
    int lm = lane & 15, quad = lane >> 4;
    int bm = blockIdx.x * 128;
    int bn = blockIdx.y * 128;

    floatx4 acc[4][4];
#pragma unroll
    for (int i = 0; i < 4; i++)
#pragma unroll
        for (int j = 0; j < 4; j++) acc[i][j] = (floatx4){0.f, 0.f, 0.f, 0.f};

    int sr = wave * 32 + (lane >> 2);
    int sk = (lane & 3) * 8;
    int ar0 = bm + sr, ar1 = ar0 + 16;
    if (ar0 > NN - 1) ar0 = NN - 1;
    if (ar1 > NN - 1) ar1 = NN - 1;
    const u16* agp0 = xb + (size_t)ar0 * KIN + sk;
    const u16* agp1 = xb + (size_t)ar1 * KIN + sk;
    const u16* bgp0 = w1t + (size_t)(bn + sr) * KIN + sk;
    const u16* bgp1 = w1t + (size_t)(bn + sr + 16) * KIN + sk;
    u16* asl0 = As + wave * 1024;
    u16* asl1 = As + wave * 1024 + 512;
    u16* bsl0 = Bs + wave * 1024;
    u16* bsl1 = Bs + wave * 1024 + 512;

    int offA[4], offB[4];
#pragma unroll
    for (int i = 0; i < 4; i++) offA[i] = (wm * 64 + i * 16 + lm) * 32 + quad * 8;
#pragma unroll
    for (int j = 0; j < 4; j++) offB[j] = (wn * 64 + j * 16 + lm) * 32 + quad * 8;

    for (int kk = 0; kk < KIN; kk += 32) {
        gll16(agp0 + kk, asl0);
        gll16(agp1 + kk, asl1);
        gll16(bgp0 + kk, bsl0);
        gll16(bgp1 + kk, bsl1);
        __syncthreads();
        shortx8 af[4], bf[4];
#pragma unroll
        for (int i = 0; i < 4; i++) af[i] = *(const shortx8*)&As[offA[i]];
#pragma unroll
        for (int j = 0; j < 4; j++) bf[j] = *(const shortx8*)&Bs[offB[j]];
#pragma unroll
        for (int i = 0; i < 4; i++)
#pragma unroll
            for (int j = 0; j < 4; j++)
                acc[i][j] = __builtin_amdgcn_mfma_f32_16x16x32_bf16(af[i], bf[j], acc[i][j], 0, 0, 0);
        __syncthreads();
    }

#pragma unroll
    for (int i = 0; i < 4; i++) {
        int row = bm + wm * 64 + i * 16 + quad * 4;
#pragma unroll
        for (int j = 0; j < 4; j++) {
            int col = bn + wn * 64 + j * 16 + lm;
#pragma unroll
            for (int r = 0; r < 4; r++) {
                if (row + r < NN) h1b[(size_t)(row + r) * HF + col] = f2bf(acc[i][j][r]);
            }
        }
    }
}

// ---------------- per-node attention scores layer 1: 8 nodes/block, 16B loads ----------------
__global__ __launch_bounds__(256) void scores1(const u16* __restrict__ h1b, const float* __restrict__ a_src,
                                               const float* __restrict__ a_dst,
                                               float* __restrict__ es, float* __restrict__ ed) {
    __shared__ float as_s[HF], ad_s[HF];
    int t = threadIdx.x;
    as_s[t] = a_src[t];
    ad_s[t] = a_dst[t];
    __syncthreads();
    int nl = t >> 5;
    int L = t & 31;
    int n = blockIdx.x * 8 + nl;
    ushortx8 hv = *(const ushortx8*)(h1b + (size_t)n * HF + L * 8);
    float ps = 0.f, pd = 0.f;
#pragma unroll
    for (int i = 0; i < 8; i++) {
        float v = bf2f(hv[i]);
        ps += v * as_s[L * 8 + i];
        pd += v * ad_s[L * 8 + i];
    }
    ps += __shfl_down(ps, 2, 4); ps += __shfl_down(ps, 1, 4);
    pd += __shfl_down(pd, 2, 4); pd += __shfl_down(pd, 1, 4);
    if ((L & 3) == 0) {
        int h = L >> 2;
        es[n * NH + h] = ps;
        ed[n * NH + h] = pd;
    }
}

// ---------------- layer-1 softmax aggregate (+ ELU), block = 1 dst node ----------------
// No max-subtraction (logits bounded ~|12|, exp safe in fp32; softmax shift-invariant).
// 256 threads: p-role = 8 heads x 32 edge-slots; agg-role = 4 waves x 64 feature-lanes (4 feat ea).
__global__ __launch_bounds__(256) void agg1(const u16* __restrict__ h1b, const float* __restrict__ es,
                                            const float* __restrict__ ed, const int* __restrict__ off,
                                            const int* __restrict__ csr_src, u16* __restrict__ out1b) {
    int n = blockIdx.x, t = threadIdx.x;
    __shared__ float edl[NH];
    __shared__ float p_chunk[32][9];    // +1 pad
    __shared__ float s_h[NH];
    __shared__ int src_chunk[32];
    __shared__ float red[4][HF];
    int beg = off[n];
    int deg = off[n + 1] - beg;
    if (t < NH) edl[t] = ed[n * NH + t];
    int ph = t >> 5, el = t & 31;       // p-role
    int w = t >> 6, L = t & 63;         // agg-role
    int ah = L >> 3;
    float s_part = 0.f;
    float acc0 = 0.f, acc1 = 0.f, acc2 = 0.f, acc3 = 0.f;
    __syncthreads();
    float edh = edl[ph];
    for (int base = 0; base < deg; base += 32) {
        int nch = deg - base; if (nch > 32) nch = 32;
        if (t < nch) src_chunk[t] = csr_src[beg + base + t];
        __syncthreads();
        // preload h1 rows (independent of p) — wave-uniform predicates, no wasted loads
        ushortx4 hv[8];
#pragma unroll
        for (int i = 0; i < 8; i++) {
            int e = w + i * 4;
            if (e < nch) hv[i] = *(const ushortx4*)(h1b + (size_t)src_chunk[e] * HF + L * 4);
        }
        // p = exp(lrelu(es+ed)), no max needed
        float p = 0.f;
        if (el < nch) p = __expf(lrelu(es[src_chunk[el] * NH + ph] + edh));
        s_part += p;
        p_chunk[el][ph] = p;
        __syncthreads();
#pragma unroll
        for (int i = 0; i < 8; i++) {
            int e = w + i * 4;
            if (e < nch) {
                float p2 = p_chunk[e][ah];
                acc0 += p2 * bf2f(hv[i][0]);
                acc1 += p2 * bf2f(hv[i][1]);
                acc2 += p2 * bf2f(hv[i][2]);
                acc3 += p2 * bf2f(hv[i][3]);
            }
        }
        __syncthreads();   // protect src_chunk/p_chunk before next chunk
    }
    // reduce s over the 32 edge-slots of each head
#pragma unroll
    for (int o = 16; o; o >>= 1) s_part += __shfl_down(s_part, o, 32);
    if (el == 0) s_h[ph] = s_part;
    *(float4*)&red[w][L * 4] = make_float4(acc0, acc1, acc2, acc3);
    __syncthreads();
    float vv = red[0][t] + red[1][t] + red[2][t] + red[3][t];
    float sh = s_h[t >> 5];
    vv *= (sh > 0.f ? 1.0f / sh : 0.f);
    out1b[(size_t)n * HF + t] = f2bf(vv > 0.f ? vv : (__expf(vv) - 1.0f));  // fused ELU
}

// ---------------- GEMM2 (1-wave MFMA) + layer-2 scores ----------------
__global__ __launch_bounds__(64) void gemm2_mfma(const u16* __restrict__ out1b, const u16* __restrict__ w2t,
                                                 const float* __restrict__ a2s, const float* __restrict__ a2d,
                                                 float* __restrict__ h2, float* __restrict__ es2,
                                                 float* __restrict__ ed2) {
    int lane = threadIdx.x;
    int lm = lane & 15, quad = lane >> 4;
    int nb = blockIdx.x * 16;
    floatx4 acc = (floatx4){0.f, 0.f, 0.f, 0.f};
    const u16* arow = out1b + (size_t)(nb + lm) * HF + quad * 8;
    const u16* brow = w2t + lm * HF + quad * 8;
#pragma unroll
    for (int kk = 0; kk < HF; kk += 32) {
        shortx8 af = *(const shortx8*)(arow + kk);
        shortx8 bf = *(const shortx8*)(brow + kk);
        acc = __builtin_amdgcn_mfma_f32_16x16x32_bf16(af, bf, acc, 0, 0, 0);
    }
    float a2sc = a2s[lm], a2dc = a2d[lm];
#pragma unroll
    for (int r = 0; r < 4; r++) {
        int n = nb + quad * 4 + r;
        float v = acc[r];
        h2[n * NC + lm] = v;
        float ps = v * a2sc, pd = v * a2dc;
#pragma unroll
        for (int o = 8; o; o >>= 1) {
            ps += __shfl_down(ps, o, 16);
            pd += __shfl_down(pd, o, 16);
        }
        if (lm == 0) { es2[n] = ps; ed2[n] = pd; }
    }
}

// ---------------- layer-2 aggregate + log_softmax: 16 nodes x 16 classes ----------------
// No max-subtraction; all 16 edge loads issued together per chunk (pipelined).
__global__ __launch_bounds__(256) void agg2(const float* __restrict__ h2, const float* __restrict__ es2,
                                            const float* __restrict__ ed2, const int* __restrict__ off,
                                            const int* __restrict__ csr_src, float* __restrict__ out) {
    int t = threadIdx.x;
    int nid = blockIdx.x * 16 + (t >> 4);   // NN % 16 == 0
    int c = t & 15;
    int beg = off[nid];
    int deg = off[nid + 1] - beg;
    float edn = ed2[nid];
    float s = 0.f, acc = 0.f;
    for (int base = 0; base < deg; base += 16) {
        int nch = deg - base; if (nch > 16) nch = 16;
        int sv = 0;
        if (c < nch) sv = csr_src[beg + base + c];
        int sva[16];
#pragma unroll
        for (int e = 0; e < 16; e++) sva[e] = __shfl(sv, e, 16);
        float hva[16];
#pragma unroll
        for (int e = 0; e < 16; e++) hva[e] = h2[sva[e] * NC + c];  // e>=nch reads row 0: masked by p=0
        float p = 0.f;
        if (c < nch) p = __expf(lrelu(es2[sv] + edn));
        s += p;
        float pa[16];
#pragma unroll
        for (int e = 0; e < 16; e++) pa[e] = __shfl(p, e, 16);
#pragma unroll
        for (int e = 0; e < 16; e++) acc += pa[e] * hva[e];
    }
#pragma unroll
    for (int o = 8; o; o >>= 1) s += __shfl_down(s, o, 16);
    s = __shfl(s, 0, 16);
    float v = (s > 0.f) ? acc / s : 0.f;
    float m2 = v;
#pragma unroll
    for (int o = 8; o; o >>= 1) m2 = fmaxf(m2, __shfl_down(m2, o, 16));
    m2 = __shfl(m2, 0, 16);
    float se = __expf(v - m2);
#pragma unroll
    for (int o = 8; o; o >>= 1) se += __shfl_down(se, o, 16);
    se = __shfl(se, 0, 16);
    out[nid * NC + c] = v - m2 - __logf(se);
}

extern "C" void kernel_launch(void* const* d_in, const int* in_sizes, int n_in,
                              void* d_out, int out_size, void* d_ws, size_t ws_size,
                              hipStream_t stream) {
    const float* x   = (const float*)d_in[0];
    const float* W1  = (const float*)d_in[1];
    const float* a1s = (const float*)d_in[2];
    const float* a1d = (const float*)d_in[3];
    const float* W2  = (const float*)d_in[4];
    const float* a2s = (const float*)d_in[5];
    const float* a2d = (const float*)d_in[6];
    const int*   ei  = (const int*)d_in[7];
    const int* srcv = ei;
    const int* dstv = ei + EE;
    float* out = (float*)d_out;

    u16* h1b   = (u16*)d_ws;                          // N*256 bf16 (25.6 MB)
    u16* xb    = h1b + (size_t)NN * HF;               // N*512 bf16 (51.2 MB)
    u16* out1b = xb;                                  // alias (xb dead after gemm1)
    float* es1 = (float*)(xb + (size_t)NN * KIN);     // N*8
    float* ed1 = es1 + (size_t)NN * NH;               // N*8
    float* h2  = ed1 + (size_t)NN * NH;               // N*16
    u16* w1t   = (u16*)h2;                            // 256*512 bf16, dead before gemm2
    float* es2v = h2 + (size_t)NN * NC;               // N
    float* ed2v = es2v + NN;                          // N
    int* deg    = (int*)(ed2v + NN);                  // N
    int* cursor = deg + NN;                           // N
    int* offs   = cursor + NN;                        // N+1
    int* csr    = offs + NN + 1;                      // E
    int* bsum   = csr + EE;                           // 256
    int* boff   = bsum + 256;                         // 256
    u16* w2t    = (u16*)(boff + 256);                 // 16*256 bf16

    hipMemsetAsync(deg, 0, NN * sizeof(int), stream);
    hipMemsetAsync(cursor, 0, NN * sizeof(int), stream);
    count_deg<<<(EE + 255) / 256, 256, 0, stream>>>(dstv, deg);
    scan_a<<<NB_SCAN, 256, 0, stream>>>(deg, bsum);
    scan_b<<<1, 256, 0, stream>>>(bsum, boff);
    scan_c<<<NB_SCAN, 256, 0, stream>>>(deg, boff, offs);
    fill_csr<<<(EE + 255) / 256, 256, 0, stream>>>(srcv, dstv, offs, cursor, csr);
    convert_x<<<((size_t)NN * KIN / 8 + 255) / 256, 256, 0, stream>>>(x, xb);
    convert_w1t<<<(KIN * HF) / 256, 256, 0, stream>>>(W1, w1t);
    convert_w2t<<<(HF * NC) / 256, 256, 0, stream>>>(W2, w2t);
    gemm1_mfma<<<dim3((NN + 127) / 128, HF / 128), 256, 0, stream>>>(xb, w1t, h1b);
    scores1<<<NN / 8, 256, 0, stream>>>(h1b, a1s, a1d, es1, ed1);
    agg1<<<NN, 256, 0, stream>>>(h1b, es1, ed1, offs, csr, out1b);
    gemm2_mfma<<<NN / 16, 64, 0, stream>>>(out1b, w2t, a2s, a2d, h2, es2v, ed2v);
    agg2<<<NN / 16, 256, 0, stream>>>(h2, es2v, ed2v, offs, csr, out);
}

// Round 6
// 360.726 us; speedup vs baseline: 2.2570x; 1.1772x over previous
//
#include <hip/hip_runtime.h>

// Problem constants (from reference)
#define NN 50000
#define EE 800000
#define KIN 512
#define HF 256      // H*OUT
#define NH 8
#define FOUT 32
#define NC 16
#define NEG 0.2f
#define NB_SCAN 196  // ceil(NN/256)

typedef unsigned short u16;
typedef __attribute__((ext_vector_type(8))) short shortx8;   // 8 bf16 (4 VGPRs) MFMA A/B frag
typedef __attribute__((ext_vector_type(4))) float floatx4;   // MFMA C/D frag
typedef __attribute__((ext_vector_type(8))) unsigned short ushortx8;
typedef __attribute__((ext_vector_type(4))) unsigned uintx4;

__device__ __forceinline__ float lrelu(float x) { return x > 0.f ? x : NEG * x; }

__device__ __forceinline__ u16 f2bf(float f) {
    unsigned u = __float_as_uint(f);
    return (u16)((u + 0x7FFFu + ((u >> 16) & 1u)) >> 16);   // RNE
}
__device__ __forceinline__ float bf2f(u16 v) {
    return __uint_as_float((unsigned)v << 16);
}
// pack two fp32 -> (bf16(a) | bf16(b)<<16), round-half-up (bias 2^-25, negligible)
__device__ __forceinline__ unsigned pk2bf(float a, float b) {
    unsigned ua = __float_as_uint(a), ub = __float_as_uint(b);
    return ((ua + 0x8000u) >> 16) | ((ub + 0x8000u) & 0xffff0000u);
}

__device__ __forceinline__ void gll16(const void* g, void* l) {
    // async global->LDS, 16B/lane; LDS dest = wave-uniform base + lane*16 (global addr per-lane OK)
    __builtin_amdgcn_global_load_lds((const __attribute__((address_space(1))) void*)g,
                                     (__attribute__((address_space(3))) void*)l, 16, 0, 0);
}

// ---------------- CSR build ----------------
__global__ void count_deg(const int* __restrict__ dst, int* __restrict__ deg) {
    int e = blockIdx.x * 256 + threadIdx.x;
    if (e < EE) atomicAdd(&deg[dst[e]], 1);
}

__global__ __launch_bounds__(256) void scan_a(const int* __restrict__ deg, int* __restrict__ bsum) {
    __shared__ int sm[256];
    int t = threadIdx.x;
    int i = blockIdx.x * 256 + t;
    sm[t] = (i < NN) ? deg[i] : 0;
    __syncthreads();
    for (int o = 128; o; o >>= 1) { if (t < o) sm[t] += sm[t + o]; __syncthreads(); }
    if (t == 0) bsum[blockIdx.x] = sm[0];
}

__global__ __launch_bounds__(256) void scan_b(const int* __restrict__ bsum, int* __restrict__ boff) {
    __shared__ int sm[256];
    int t = threadIdx.x;
    sm[t] = (t < NB_SCAN) ? bsum[t] : 0;
    __syncthreads();
    for (int d = 1; d < 256; d <<= 1) {
        int v = (t >= d) ? sm[t - d] : 0;
        __syncthreads();
        sm[t] += v;
        __syncthreads();
    }
    if (t < NB_SCAN) boff[t] = (t == 0) ? 0 : sm[t - 1];
}

__global__ __launch_bounds__(256) void scan_c(const int* __restrict__ deg, const int* __restrict__ boff,
                                              int* __restrict__ off) {
    __shared__ int sm[256];
    int t = threadIdx.x;
    int i = blockIdx.x * 256 + t;
    int d = (i < NN) ? deg[i] : 0;
    sm[t] = d;
    __syncthreads();
    for (int dd = 1; dd < 256; dd <<= 1) {
        int v = (t >= dd) ? sm[t - dd] : 0;
        __syncthreads();
        sm[t] += v;
        __syncthreads();
    }
    if (i < NN) off[i] = boff[blockIdx.x] + sm[t] - d;
    if (i == 0) off[NN] = EE;
}

__global__ void fill_csr(const int* __restrict__ src, const int* __restrict__ dst,
                         const int* __restrict__ off, int* __restrict__ cursor,
                         int* __restrict__ csr_src) {
    int e = blockIdx.x * 256 + threadIdx.x;
    if (e < EE) {
        int d = dst[e];
        int pos = atomicAdd(&cursor[d], 1);
        csr_src[off[d] + pos] = src[e];
    }
}

// ---------------- weight converts (merged) ----------------
// W1 [512,256] -> w1t [256,512] bf16 ; W2 [256,16] -> w2t [16,256] bf16
__global__ __launch_bounds__(256) void convert_w(const float* __restrict__ W1, const float* __restrict__ W2,
                                                 u16* __restrict__ w1t, u16* __restrict__ w2t) {
    int e = blockIdx.x * 256 + threadIdx.x;
    if (e < KIN * HF) {
        int k = e >> 8, n = e & 255;
        w1t[n * KIN + k] = f2bf(W1[e]);
    } else {
        int e2 = e - KIN * HF;
        if (e2 < HF * NC) {
            int k = e2 >> 4, c = e2 & 15;
            w2t[c * HF + k] = f2bf(W2[e2]);
        }
    }
}

// ---------------- GEMM1 (bf16 MFMA, fused x-convert): h1b[N,256] = bf16(x)[N,512] @ W1T^T ----------------
// Tile 128x256 (full width -> x staged & converted exactly once). A staged fp32 via gll16,
// packed to bf16 at frag read. 4 waves, each 64 rows x 128 cols = 4x8 MFMA tiles.
__global__ __launch_bounds__(256, 2) void gemm1_mfma(const float* __restrict__ x,
                                                     const u16* __restrict__ w1t,
                                                     u16* __restrict__ h1b) {
    __shared__ __align__(16) float As[128 * 32];   // [row][k] fp32, 16 KB
    __shared__ __align__(16) u16 Bs[256 * 32];     // [col][k] bf16, 16 KB
    int t = threadIdx.x;
    int lane = t & 63, wave = t >> 6;
    int wm = wave >> 1, wn = wave & 1;
    int lm = lane & 15, quad = lane >> 4;
    int bm = blockIdx.x * 128;

    floatx4 acc[4][8];
#pragma unroll
    for (int i = 0; i < 4; i++)
#pragma unroll
        for (int j = 0; j < 8; j++) acc[i][j] = (floatx4){0.f, 0.f, 0.f, 0.f};

    // A staging: wave covers rows wave*32..+31 ; 4 insts x 8 rows (fp32, 4 floats/lane)
    int arow_l = wave * 32 + (lane >> 3);
    int akoff = (lane & 7) * 4;
    const float* aptr[4];
#pragma unroll
    for (int i = 0; i < 4; i++) {
        int ar = bm + arow_l + i * 8;
        if (ar > NN - 1) ar = NN - 1;     // tail dup-reads; C-write guarded
        aptr[i] = x + (size_t)ar * KIN + akoff;
    }
    float* alds[4];
#pragma unroll
    for (int i = 0; i < 4; i++) alds[i] = As + (wave * 32 + i * 8) * 32;

    // B staging: wave covers cols wave*64..+63 ; 4 insts x 16 rows (bf16, 8 elems/lane)
    int brow_l = wave * 64 + (lane >> 2);
    int bkoff = (lane & 3) * 8;
    const u16* bptr[4];
#pragma unroll
    for (int i = 0; i < 4; i++) bptr[i] = w1t + (size_t)(brow_l + i * 16) * KIN + bkoff;
    u16* blds[4];
#pragma unroll
    for (int i = 0; i < 4; i++) blds[i] = Bs + (wave * 64 + i * 16) * 32;

    int offA[4], offB[8];
#pragma unroll
    for (int i = 0; i < 4; i++) offA[i] = (wm * 64 + i * 16 + lm) * 32 + quad * 8;
#pragma unroll
    for (int j = 0; j < 8; j++) offB[j] = (wn * 128 + j * 16 + lm) * 32 + quad * 8;

    for (int kk = 0; kk < KIN; kk += 32) {
#pragma unroll
        for (int i = 0; i < 4; i++) gll16(aptr[i] + kk, alds[i]);
#pragma unroll
        for (int i = 0; i < 4; i++) gll16(bptr[i] + kk, blds[i]);
        __syncthreads();
        shortx8 af[4], bf[8];
#pragma unroll
        for (int i = 0; i < 4; i++) {
            const float4* ap = (const float4*)&As[offA[i]];
            float4 lo = ap[0], hi = ap[1];
            union { uintx4 u; shortx8 s; } cv;
            cv.u[0] = pk2bf(lo.x, lo.y);
            cv.u[1] = pk2bf(lo.z, lo.w);
            cv.u[2] = pk2bf(hi.x, hi.y);
            cv.u[3] = pk2bf(hi.z, hi.w);
            af[i] = cv.s;
        }
#pragma unroll
        for (int j = 0; j < 8; j++) bf[j] = *(const shortx8*)&Bs[offB[j]];
#pragma unroll
        for (int i = 0; i < 4; i++)
#pragma unroll
            for (int j = 0; j < 8; j++)
                acc[i][j] = __builtin_amdgcn_mfma_f32_16x16x32_bf16(af[i], bf[j], acc[i][j], 0, 0, 0);
        __syncthreads();
    }

    // epilogue: C/D map col=lane&15, row=quad*4+reg -> bf16
#pragma unroll
    for (int i = 0; i < 4; i++) {
        int row = bm + wm * 64 + i * 16 + quad * 4;
#pragma unroll
        for (int j = 0; j < 8; j++) {
            int col = wn * 128 + j * 16 + lm;
#pragma unroll
            for (int r = 0; r < 4; r++) {
                if (row + r < NN) h1b[(size_t)(row + r) * HF + col] = f2bf(acc[i][j][r]);
            }
        }
    }
}

// ---------------- per-node attention scores layer 1: 8 nodes/block, 16B loads ----------------
__global__ __launch_bounds__(256) void scores1(const u16* __restrict__ h1b, const float* __restrict__ a_src,
                                               const float* __restrict__ a_dst,
                                               float* __restrict__ es, float* __restrict__ ed) {
    __shared__ float as_s[HF], ad_s[HF];
    int t = threadIdx.x;
    as_s[t] = a_src[t];
    ad_s[t] = a_dst[t];
    __syncthreads();
    int nl = t >> 5;
    int L = t & 31;
    int n = blockIdx.x * 8 + nl;
    ushortx8 hv = *(const ushortx8*)(h1b + (size_t)n * HF + L * 8);
    float ps = 0.f, pd = 0.f;
#pragma unroll
    for (int i = 0; i < 8; i++) {
        float v = bf2f(hv[i]);
        ps += v * as_s[L * 8 + i];
        pd += v * ad_s[L * 8 + i];
    }
    ps += __shfl_down(ps, 2, 4); ps += __shfl_down(ps, 1, 4);
    pd += __shfl_down(pd, 2, 4); pd += __shfl_down(pd, 1, 4);
    if ((L & 3) == 0) {
        int h = L >> 2;
        es[n * NH + h] = ps;
        ed[n * NH + h] = pd;
    }
}

// ---------------- layer-1 softmax aggregate (+ ELU): 1 wave = 1 node, NO barriers/LDS ----------------
// lane = 32 feature-octets x 2 edge-parities. No max-subtraction (logits bounded, shift-invariant).
__global__ __launch_bounds__(256) void agg1(const u16* __restrict__ h1b, const float* __restrict__ es,
                                            const float* __restrict__ ed, const int* __restrict__ off,
                                            const int* __restrict__ csr_src, u16* __restrict__ out1b) {
    int wave = threadIdx.x >> 6;
    int lane = threadIdx.x & 63;
    int n = blockIdx.x * 4 + wave;      // NN % 4 == 0
    int fh = lane & 31;                 // features fh*8 .. fh*8+7
    int ep = lane >> 5;                 // edge parity
    int head = fh >> 2;
    int beg = off[n];
    int deg = off[n + 1] - beg;
    float edh = ed[n * NH + head];
    const u16* hbase = h1b + fh * 8;
    float acc[8] = {0.f, 0.f, 0.f, 0.f, 0.f, 0.f, 0.f, 0.f};
    float s_part = 0.f;
    for (int base = 0; base < deg; base += 16) {
        int nch = deg - base; if (nch > 16) nch = 16;
        int sv = (lane < nch) ? csr_src[beg + base + lane] : 0;
#pragma unroll
        for (int e = 0; e < 8; e++) {
            int ee = 2 * e + ep;
            int s = __shfl(sv, ee, 64);
            if (ee < nch) {
                float lg = es[s * NH + head] + edh;
                float p = __expf(lg > 0.f ? lg : NEG * lg);
                ushortx8 hv = *(const ushortx8*)(hbase + (size_t)s * HF);
                s_part += p;
#pragma unroll
                for (int i = 0; i < 8; i++) acc[i] += p * bf2f(hv[i]);
            }
        }
    }
    // combine parities: lanes 0..31 get totals
#pragma unroll
    for (int i = 0; i < 8; i++) acc[i] += __shfl_down(acc[i], 32, 64);
    s_part += __shfl_down(s_part, 32, 64);
    if (lane < 32) {
        float inv = s_part > 0.f ? 1.0f / s_part : 0.f;
        union { uintx4 u; ushortx8 v; } ob;
#pragma unroll
        for (int i = 0; i < 4; i++) {
            float v0 = acc[2 * i] * inv, v1 = acc[2 * i + 1] * inv;
            v0 = v0 > 0.f ? v0 : (__expf(v0) - 1.0f);   // fused ELU
            v1 = v1 > 0.f ? v1 : (__expf(v1) - 1.0f);
            ob.u[i] = (unsigned)f2bf(v0) | ((unsigned)f2bf(v1) << 16);
        }
        *(ushortx8*)(out1b + (size_t)n * HF + fh * 8) = ob.v;
    }
}

// ---------------- GEMM2 (1-wave MFMA) + layer-2 scores ----------------
__global__ __launch_bounds__(64) void gemm2_mfma(const u16* __restrict__ out1b, const u16* __restrict__ w2t,
                                                 const float* __restrict__ a2s, const float* __restrict__ a2d,
                                                 float* __restrict__ h2, float* __restrict__ es2,
                                                 float* __restrict__ ed2) {
    int lane = threadIdx.x;
    int lm = lane & 15, quad = lane >> 4;
    int nb = blockIdx.x * 16;
    floatx4 acc = (floatx4){0.f, 0.f, 0.f, 0.f};
    const u16* arow = out1b + (size_t)(nb + lm) * HF + quad * 8;
    const u16* brow = w2t + lm * HF + quad * 8;
#pragma unroll
    for (int kk = 0; kk < HF; kk += 32) {
        shortx8 af = *(const shortx8*)(arow + kk);
        shortx8 bf = *(const shortx8*)(brow + kk);
        acc = __builtin_amdgcn_mfma_f32_16x16x32_bf16(af, bf, acc, 0, 0, 0);
    }
    float a2sc = a2s[lm], a2dc = a2d[lm];
#pragma unroll
    for (int r = 0; r < 4; r++) {
        int n = nb + quad * 4 + r;
        float v = acc[r];
        h2[n * NC + lm] = v;
        float ps = v * a2sc, pd = v * a2dc;
#pragma unroll
        for (int o = 8; o; o >>= 1) {
            ps += __shfl_down(ps, o, 16);
            pd += __shfl_down(pd, o, 16);
        }
        if (lm == 0) { es2[n] = ps; ed2[n] = pd; }
    }
}

// ---------------- layer-2 aggregate + log_softmax: 16 nodes x 16 classes ----------------
__global__ __launch_bounds__(256) void agg2(const float* __restrict__ h2, const float* __restrict__ es2,
                                            const float* __restrict__ ed2, const int* __restrict__ off,
                                            const int* __restrict__ csr_src, float* __restrict__ out) {
    int t = threadIdx.x;
    int nid = blockIdx.x * 16 + (t >> 4);   // NN % 16 == 0
    int c = t & 15;
    int beg = off[nid];
    int deg = off[nid + 1] - beg;
    float edn = ed2[nid];
    float s = 0.f, acc = 0.f;
    for (int base = 0; base < deg; base += 16) {
        int nch = deg - base; if (nch > 16) nch = 16;
        int sv = 0;
        if (c < nch) sv = csr_src[beg + base + c];
        int sva[16];
#pragma unroll
        for (int e = 0; e < 16; e++) sva[e] = __shfl(sv, e, 16);
        float hva[16];
#pragma unroll
        for (int e = 0; e < 16; e++) hva[e] = h2[sva[e] * NC + c];  // e>=nch reads row 0: masked by p=0
        float p = 0.f;
        if (c < nch) p = __expf(lrelu(es2[sv] + edn));
        s += p;
        float pa[16];
#pragma unroll
        for (int e = 0; e < 16; e++) pa[e] = __shfl(p, e, 16);
#pragma unroll
        for (int e = 0; e < 16; e++) acc += pa[e] * hva[e];
    }
#pragma unroll
    for (int o = 8; o; o >>= 1) s += __shfl_down(s, o, 16);
    s = __shfl(s, 0, 16);
    float v = (s > 0.f) ? acc / s : 0.f;
    float m2 = v;
#pragma unroll
    for (int o = 8; o; o >>= 1) m2 = fmaxf(m2, __shfl_down(m2, o, 16));
    m2 = __shfl(m2, 0, 16);
    float se = __expf(v - m2);
#pragma unroll
    for (int o = 8; o; o >>= 1) se += __shfl_down(se, o, 16);
    se = __shfl(se, 0, 16);
    out[nid * NC + c] = v - m2 - __logf(se);
}

extern "C" void kernel_launch(void* const* d_in, const int* in_sizes, int n_in,
                              void* d_out, int out_size, void* d_ws, size_t ws_size,
                              hipStream_t stream) {
    const float* x   = (const float*)d_in[0];
    const float* W1  = (const float*)d_in[1];
    const float* a1s = (const float*)d_in[2];
    const float* a1d = (const float*)d_in[3];
    const float* W2  = (const float*)d_in[4];
    const float* a2s = (const float*)d_in[5];
    const float* a2d = (const float*)d_in[6];
    const int*   ei  = (const int*)d_in[7];
    const int* srcv = ei;
    const int* dstv = ei + EE;
    float* out = (float*)d_out;

    // workspace (~62 MB)
    u16* h1b    = (u16*)d_ws;                         // N*256 bf16
    u16* out1b  = h1b + (size_t)NN * HF;              // N*256 bf16
    float* es1  = (float*)(out1b + (size_t)NN * HF);  // N*8
    float* ed1  = es1 + (size_t)NN * NH;              // N*8
    float* h2   = ed1 + (size_t)NN * NH;              // N*16
    float* es2v = h2 + (size_t)NN * NC;               // N
    float* ed2v = es2v + NN;                          // N
    int* deg    = (int*)(ed2v + NN);                  // N   (deg+cursor contiguous: one memset)
    int* cursor = deg + NN;                           // N
    int* offs   = cursor + NN;                        // N+1
    int* csr    = offs + NN + 1;                      // E
    int* bsum   = csr + EE;                           // 256
    int* boff   = bsum + 256;                         // 256
    u16* w1t    = (u16*)(boff + 256);                 // 256*512 bf16
    u16* w2t    = w1t + (size_t)HF * KIN;             // 16*256 bf16

    hipMemsetAsync(deg, 0, 2 * NN * sizeof(int), stream);
    count_deg<<<(EE + 255) / 256, 256, 0, stream>>>(dstv, deg);
    scan_a<<<NB_SCAN, 256, 0, stream>>>(deg, bsum);
    scan_b<<<1, 256, 0, stream>>>(bsum, boff);
    scan_c<<<NB_SCAN, 256, 0, stream>>>(deg, boff, offs);
    fill_csr<<<(EE + 255) / 256, 256, 0, stream>>>(srcv, dstv, offs, cursor, csr);
    convert_w<<<(KIN * HF + HF * NC + 255) / 256, 256, 0, stream>>>(W1, W2, w1t, w2t);
    gemm1_mfma<<<(NN + 127) / 128, 256, 0, stream>>>(x, w1t, h1b);
    scores1<<<NN / 8, 256, 0, stream>>>(h1b, a1s, a1d, es1, ed1);
    agg1<<<NN / 4, 256, 0, stream>>>(h1b, es1, ed1, offs, csr, out1b);
    gemm2_mfma<<<NN / 16, 64, 0, stream>>>(out1b, w2t, a2s, a2d, h2, es2v, ed2v);
    agg2<<<NN / 16, 256, 0, stream>>>(h2, es2v, ed2v, offs, csr, out);
}